// Round 18
// baseline (570.833 us; speedup 1.0000x reference)
//
#include <hip/hip_runtime.h>

#define BN 8
#define NP 2048
#define KK 20
#define EPSV 1e-5f

typedef __attribute__((ext_vector_type(8))) short bf16x8;
typedef __attribute__((ext_vector_type(4))) float f32x4;

static __device__ __forceinline__ float leakyf(float v){ return v >= 0.f ? v : 0.2f*v; }
static __device__ __forceinline__ unsigned fenc(float f){
  unsigned u = __float_as_uint(f);
  unsigned m = (unsigned)((int)u >> 31);
  return u ^ (m | 0x80000000u);
}
static __device__ __forceinline__ float fdec(unsigned u){
  return __uint_as_float((u & 0x80000000u) ? (u & 0x7FFFFFFFu) : ~u);
}
static __device__ __forceinline__ unsigned bf2(float a, float b){
  unsigned ua = __float_as_uint(a), ub = __float_as_uint(b);
  ua = (ua + 0x7FFFu + ((ua>>16)&1u)) >> 16;
  ub = (ub + 0x7FFFu + ((ub>>16)&1u)) >> 16;
  return ua | (ub<<16);
}
static __device__ __forceinline__ unsigned short b16(float v){
  unsigned u = __float_as_uint(v);
  return (unsigned short)((u + 0x7FFFu + ((u>>16)&1u)) >> 16);
}
static __device__ __forceinline__ unsigned umax32(unsigned a, unsigned b){ return __builtin_elementwise_max(a,b); }
static __device__ __forceinline__ unsigned med3u(unsigned a, unsigned b, unsigned c){
  unsigned d;
  asm("v_med3_u32 %0, %1, %2, %3" : "=v"(d) : "v"(a), "v"(b), "v"(c));
  return d;
}

// LDS addressing for mgemm fp32-staged path: 80B rows, XOR swizzle on bits 4-5.
static __device__ __forceinline__ char* ldsW(char* base, int row, int colb){
  return base + row*80 + (colb ^ ((((unsigned)row>>3)&3u)<<4));
}
static __device__ __forceinline__ char* ldsX(char* base, int row, int colb){
  return base + row*80 + (colb ^ (((((unsigned)row>>2)^((unsigned)row>>4))&3u)<<4));
}
static __device__ __forceinline__ int swz128(int row, int colb){
  return (colb ^ ((row&7)<<4));
}

// ---------------- weight -> bf16 mirror (one-time) ----------------
__global__ __launch_bounds__(256) void wprep_kernel(const float* __restrict__ W, int ldw, int O,
                                                    unsigned short* __restrict__ out){
  long i = (long)blockIdx.x*256 + threadIdx.x;
  if (i < (long)O*256){
    int o = (int)(i >> 8), c = (int)(i & 255);
    out[i] = b16(W[(long)o*ldw + c]);
  }
}

// ---------------- xx = sum_c x^2 (block1 only, on raw x) ----------------
__global__ __launch_bounds__(256) void xx_kernel(const float* __restrict__ x, long ldb, int C,
                                                 float* __restrict__ xx){
  int b = blockIdx.y;
  int n = blockIdx.x*256 + threadIdx.x;
  const float* xp = x + (long)b*ldb + n;
  float a = 0.f;
  for(int c=0;c<C;c++){ float v = xp[(long)c*NP]; a += v*v; }
  xx[b*NP + n] = a;
}

// ---------------- branch-free u32 key insert: 1 med3 per position ----------------
static __device__ __forceinline__ void ins20(unsigned* tv, unsigned key){
  unsigned pold = tv[0];
  tv[0] = umax32(tv[0], key);
  #pragma unroll
  for(int r=1;r<20;r++){
    unsigned cold = tv[r];
    tv[r] = med3u(key, pold, cold);
    pold = cold;
  }
}

// ---------------- knn C=64: LDS-staged candidates; mirrors fh[b][n][256], fl[b][n][128] ----------------
__global__ __launch_bounds__(256) void knnf_kernel(const unsigned short* __restrict__ fh,
                                                   const unsigned short* __restrict__ fl,
                                                   int cbase,
                                                   const float* __restrict__ xx,
                                                   unsigned* __restrict__ pk){
  __shared__ unsigned short CH[64][68];
  __shared__ unsigned short CL[64][68];
  __shared__ unsigned SK[64][68];
  __shared__ float cxs[64];
  const int b    = blockIdx.z;
  const int part = blockIdx.y;
  const int q0   = blockIdx.x*64;
  const int t    = threadIdx.x;
  const int lane = t & 63;
  const int w    = t >> 6;
  const int lr   = lane & 15, lg = lane >> 4;
  const unsigned short* fhb = fh + (long)b*NP*256;
  const unsigned short* flb = fl + (long)b*NP*128;
  const float* xxb = xx + b*NP;

  const unsigned short* qa = fhb + ((long)(q0 + w*16 + lr))*256 + cbase + lg*8;
  const unsigned short* qb = flb + ((long)(q0 + w*16 + lr))*128 + cbase + lg*8;
  bf16x8 ah0 = *(const bf16x8*)(qa);
  bf16x8 ah1 = *(const bf16x8*)(qa + 32);
  bf16x8 al0 = *(const bf16x8*)(qb);
  bf16x8 al1 = *(const bf16x8*)(qb + 32);
  float4 qxx4 = *(const float4*)(xxb + q0 + w*16 + lg*4);
  float qxx[4] = {qxx4.x, qxx4.y, qxx4.z, qxx4.w};

  unsigned tv[20];
  #pragma unroll
  for(int r=0;r<20;r++) tv[r] = 0u;
  const int sq = t>>2, sl = t&3;

  #define STAGE(ct_)                                                                        \
    {                                                                                       \
      const int ct__ = (ct_);                                                               \
      _Pragma("unroll")                                                                     \
      for(int i = t; i < 512; i += 256){                                                    \
        int row = i >> 3, seg = i & 7;                                                      \
        *(uint4*)&CH[row][seg*8] = *(const uint4*)(fhb + ((long)(ct__*64+row))*256 + cbase + seg*8); \
        *(uint4*)&CL[row][seg*8] = *(const uint4*)(flb + ((long)(ct__*64+row))*128 + cbase + seg*8); \
      }                                                                                     \
      if (t < 64) cxs[t] = xxb[ct__*64 + t];                                                \
    }

  STAGE(part*4);
  __syncthreads();

  #pragma unroll
  for(int cc=0; cc<4; cc++){
    __builtin_amdgcn_s_setprio(1);
    f32x4 acc[4];
    #pragma unroll
    for(int nt=0; nt<4; nt++){
      int crow = nt*16 + lr;
      bf16x8 bh0 = *(const bf16x8*)&CH[crow][lg*8];
      bf16x8 bh1 = *(const bf16x8*)&CH[crow][32 + lg*8];
      bf16x8 bl0 = *(const bf16x8*)&CL[crow][lg*8];
      bf16x8 bl1 = *(const bf16x8*)&CL[crow][32 + lg*8];
      f32x4 a = (f32x4){0.f,0.f,0.f,0.f};
      a = __builtin_amdgcn_mfma_f32_16x16x32_bf16(ah0, bh0, a, 0,0,0);
      a = __builtin_amdgcn_mfma_f32_16x16x32_bf16(ah1, bh1, a, 0,0,0);
      a = __builtin_amdgcn_mfma_f32_16x16x32_bf16(ah0, bl0, a, 0,0,0);
      a = __builtin_amdgcn_mfma_f32_16x16x32_bf16(ah1, bl1, a, 0,0,0);
      a = __builtin_amdgcn_mfma_f32_16x16x32_bf16(al0, bh0, a, 0,0,0);
      a = __builtin_amdgcn_mfma_f32_16x16x32_bf16(al1, bh1, a, 0,0,0);
      acc[nt] = a;
    }
    __builtin_amdgcn_s_setprio(0);
    float cxv[4];
    #pragma unroll
    for(int nt=0; nt<4; nt++) cxv[nt] = cxs[nt*16 + lr];
    unsigned key4[4][4];
    #pragma unroll
    for(int nt=0; nt<4; nt++){
      #pragma unroll
      for(int r=0;r<4;r++){
        float neg = 2.f*acc[nt][r] - qxx[r] - cxv[nt];
        key4[nt][r] = (fenc(neg) & 0xFFFFFF00u) | (255u - (unsigned)(cc*64 + nt*16 + lr));
      }
    }
    __syncthreads();
    #pragma unroll
    for(int nt=0; nt<4; nt++)
      #pragma unroll
      for(int r=0;r<4;r++)
        SK[w*16 + lg*4 + r][nt*16 + lr] = key4[nt][r];
    if (cc < 3){
      STAGE(part*4 + cc + 1);
    }
    __syncthreads();
    #pragma unroll
    for(int jj=0;jj<4;jj++){
      uint4 kv = *(const uint4*)&SK[sq][sl*16 + jj*4];
      ins20(tv, kv.x); ins20(tv, kv.y); ins20(tv, kv.z); ins20(tv, kv.w);
    }
  }
  #undef STAGE
  long base = ((((long)b*NP + q0 + sq)*8 + part)*4 + sl)*20;
  #pragma unroll
  for(int r=0;r<20;r++) pk[base+r] = tv[r];
}

// ---------------- knn C=3 direct ----------------
__global__ __launch_bounds__(256) void knn1_kernel(const float* __restrict__ x,
                                                   const float* __restrict__ xx,
                                                   unsigned* __restrict__ pk){
  __shared__ float cx0[256], cx1[256], cx2[256], cxxa[256];
  const int b    = blockIdx.z;
  const int part = blockIdx.y;
  const int q0   = blockIdx.x*64;
  const int t    = threadIdx.x;
  const float* xb  = x + (long)b*3*NP;
  const float* xxb = xx + b*NP;

  cx0[t]  = xb[part*256 + t];
  cx1[t]  = xb[NP + part*256 + t];
  cx2[t]  = xb[2*NP + part*256 + t];
  cxxa[t] = xxb[part*256 + t];

  const int sq = t>>2, sl = t&3;
  const int q = q0 + sq;
  float qx = xb[q], qy = xb[NP + q], qz = xb[2*NP + q];
  float qxx = xxb[q];
  __syncthreads();

  unsigned tv[20];
  #pragma unroll
  for(int r=0;r<20;r++) tv[r] = 0u;

  for(int cc=0; cc<4; cc++){
    #pragma unroll
    for(int j=0;j<16;j++){
      int m = cc*64 + sl*16 + j;
      float ip = qx*cx0[m] + qy*cx1[m] + qz*cx2[m];
      float neg = 2.f*ip - qxx - cxxa[m];
      unsigned key = (fenc(neg) & 0xFFFFFF00u) | (255u - (unsigned)m);
      ins20(tv, key);
    }
  }
  long base = ((((long)b*NP + q0 + sq)*8 + part)*4 + sl)*20;
  #pragma unroll
  for(int r=0;r<20;r++) pk[base+r] = tv[r];
}

// ---------------- wave-parallel merge ----------------
__global__ __launch_bounds__(256) void knnmerge_kernel(const unsigned* __restrict__ pk,
                                                       int* __restrict__ idxout){
  const int wid  = threadIdx.x >> 6;
  const int lane = threadIdx.x & 63;
  const long qg = (long)blockIdx.x*4 + wid;
  const unsigned* kb = pk + qg*640;
  const int l = lane >> 1, h = lane & 1;
  unsigned k[10];
  {
    const unsigned* src = kb + l*20 + h*10;
    #pragma unroll
    for(int i=0;i<10;i++) k[i] = src[i];
  }
  int rem = 10;
  int* op = idxout + qg*KK;
  const int gbase = (l>>2)*256;
  for(int r=0;r<KK;r++){
    unsigned key = k[0];
    int gi = gbase + 255 - (int)(key & 255u);
    unsigned long long cmp = (rem > 0)
        ? ((unsigned long long)(key & 0xFFFFFF00u) << 32) | (unsigned)(0x7FFFFFFF - gi)
        : 0ull;
    unsigned long long w = cmp;
    #pragma unroll
    for(int s=1;s<64;s<<=1){
      unsigned long long o = __shfl_xor(w, s, 64);
      w = (o > w) ? o : w;
    }
    if (lane == 0){
      op[r] = 0x7FFFFFFF - (int)(unsigned)(w & 0xFFFFFFFFu);
    }
    if (cmp == w){
      #pragma unroll
      for(int i=0;i<9;i++) k[i] = k[i+1];
      rem--;
    }
  }
}

// ---------------- edge conv C=3: vector ----------------
template<int CIN, int O>
__global__ __launch_bounds__(256) void pcdual_kernel(const float* __restrict__ x, long ldb,
                                                     const float* __restrict__ W,
                                                     float* __restrict__ ya, float* __restrict__ dd){
  __shared__ float Wt[CIN][O+1];
  constexpr int NLOC = 256/O;
  const int b = blockIdx.y;
  const int n0 = blockIdx.x*NLOC;
  const int t = threadIdx.x;
  const int o = t % O;
  const int n = n0 + t/O;
  const float* xp = x + (long)b*ldb + n;
  float xv[CIN];
  #pragma unroll
  for(int c=0;c<CIN;c++) xv[c] = xp[(long)c*NP];
  for(int i=t;i<CIN*O;i+=256){ int oo=i/CIN, c=i%CIN; Wt[c][oo] = W[(long)oo*2*CIN + c]; }
  __syncthreads();
  float aa = 0.f;
  #pragma unroll
  for(int c=0;c<CIN;c++) aa += Wt[c][o]*xv[c];
  __syncthreads();
  for(int i=t;i<CIN*O;i+=256){ int oo=i/CIN, c=i%CIN; Wt[c][oo] = W[(long)oo*2*CIN + CIN + c]; }
  __syncthreads();
  float ab = 0.f;
  #pragma unroll
  for(int c=0;c<CIN;c++) ab += Wt[c][o]*xv[c];
  long outoff = ((long)b*NP + n)*O + o;
  ya[outoff] = aa;
  dd[outoff] = ab - aa;
}

// ---------------- edge conv C=64 via MFMA from mirrors ----------------
template<int O>
__global__ __launch_bounds__(256) void pcdualm_kernel(const unsigned short* __restrict__ fh,
                                                      const unsigned short* __restrict__ fl,
                                                      int cbase,
                                                      const float* __restrict__ W,
                                                      float* __restrict__ ya, float* __restrict__ dd){
  __shared__ unsigned short AH[O][64];
  __shared__ unsigned short AL[O][64];
  __shared__ unsigned short DH[O][64];
  __shared__ unsigned short DL[O][64];
  const int b  = blockIdx.y;
  const int n0 = blockIdx.x*64;
  const int t  = threadIdx.x;
  const int lane = t & 63;
  const int w  = t >> 6;
  const int lr = lane & 15, lg = lane >> 4;

  for(int i=t; i<O*64; i+=256){
    int o = i >> 6, c = i & 63;
    float va = W[(long)o*128 + c];
    float vb = W[(long)o*128 + 64 + c];
    float vd = vb - va;
    unsigned short ah = b16(va);
    unsigned short dh = b16(vd);
    int byt = swz128(o, c*2);
    *(unsigned short*)((char*)&AH[o][0] + byt) = ah;
    *(unsigned short*)((char*)&AL[o][0] + byt) = b16(va - __uint_as_float(((unsigned)ah)<<16));
    *(unsigned short*)((char*)&DH[o][0] + byt) = dh;
    *(unsigned short*)((char*)&DL[o][0] + byt) = b16(vd - __uint_as_float(((unsigned)dh)<<16));
  }

  const int n = n0 + w*16 + lr;
  const unsigned short* xh = fh + ((long)b*NP + n)*256 + cbase + lg*8;
  const unsigned short* xl = fl + ((long)b*NP + n)*128 + cbase + lg*8;
  bf16x8 xh0 = *(const bf16x8*)(xh);
  bf16x8 xh1 = *(const bf16x8*)(xh + 32);
  bf16x8 xl0 = *(const bf16x8*)(xl);
  bf16x8 xl1 = *(const bf16x8*)(xl + 32);
  __syncthreads();

  #pragma unroll
  for(int mi=0; mi<O/16; mi++){
    int row = mi*16 + lr;
    bf16x8 a_h0 = *(const bf16x8*)((char*)&AH[row][0] + swz128(row, lg*16));
    bf16x8 a_h1 = *(const bf16x8*)((char*)&AH[row][0] + swz128(row, 64 + lg*16));
    bf16x8 a_l0 = *(const bf16x8*)((char*)&AL[row][0] + swz128(row, lg*16));
    bf16x8 a_l1 = *(const bf16x8*)((char*)&AL[row][0] + swz128(row, 64 + lg*16));
    f32x4 aa = (f32x4){0.f,0.f,0.f,0.f};
    aa = __builtin_amdgcn_mfma_f32_16x16x32_bf16(a_h0, xh0, aa, 0,0,0);
    aa = __builtin_amdgcn_mfma_f32_16x16x32_bf16(a_h1, xh1, aa, 0,0,0);
    aa = __builtin_amdgcn_mfma_f32_16x16x32_bf16(a_h0, xl0, aa, 0,0,0);
    aa = __builtin_amdgcn_mfma_f32_16x16x32_bf16(a_h1, xl1, aa, 0,0,0);
    aa = __builtin_amdgcn_mfma_f32_16x16x32_bf16(a_l0, xh0, aa, 0,0,0);
    aa = __builtin_amdgcn_mfma_f32_16x16x32_bf16(a_l1, xh1, aa, 0,0,0);
    bf16x8 d_h0 = *(const bf16x8*)((char*)&DH[row][0] + swz128(row, lg*16));
    bf16x8 d_h1 = *(const bf16x8*)((char*)&DH[row][0] + swz128(row, 64 + lg*16));
    bf16x8 d_l0 = *(const bf16x8*)((char*)&DL[row][0] + swz128(row, lg*16));
    bf16x8 d_l1 = *(const bf16x8*)((char*)&DL[row][0] + swz128(row, 64 + lg*16));
    f32x4 ad = (f32x4){0.f,0.f,0.f,0.f};
    ad = __builtin_amdgcn_mfma_f32_16x16x32_bf16(d_h0, xh0, ad, 0,0,0);
    ad = __builtin_amdgcn_mfma_f32_16x16x32_bf16(d_h1, xh1, ad, 0,0,0);
    ad = __builtin_amdgcn_mfma_f32_16x16x32_bf16(d_h0, xl0, ad, 0,0,0);
    ad = __builtin_amdgcn_mfma_f32_16x16x32_bf16(d_h1, xl1, ad, 0,0,0);
    ad = __builtin_amdgcn_mfma_f32_16x16x32_bf16(d_l0, xh0, ad, 0,0,0);
    ad = __builtin_amdgcn_mfma_f32_16x16x32_bf16(d_l1, xh1, ad, 0,0,0);
    long ooff = ((long)b*NP + n)*O + mi*16 + lg*4;
    float4 va = {aa[0],aa[1],aa[2],aa[3]};
    float4 vd = {ad[0],ad[1],ad[2],ad[3]};
    *(float4*)(ya + ooff) = va;
    *(float4*)(dd + ooff) = vd;
  }
}

// ---------------- edge gather v3 ----------------
template<int O>
__global__ __launch_bounds__(256) void egather_kernel(const float* __restrict__ ya, const float* __restrict__ dd,
                               const int* __restrict__ idx,
                               float* __restrict__ mx, float* __restrict__ mn,
                               float* __restrict__ stats){
  __shared__ float sred2[4][16];
  constexpr int NSUB = 256/O;
  constexpr int CPG = O/8;
  const int b  = blockIdx.x & 7;
  const int n0 = (blockIdx.x >> 3) * 32;
  const int t = threadIdx.x;
  const int w = t >> 6;
  const int o = t % O;
  const int ns = t / O;
  if (t < 64) sred2[t>>4][t&15] = 0.f;
  __syncthreads();
  float gs = 0.f, gs2 = 0.f;
  const float* yab = ya + (long)b*NP*O;
  for(int p=ns; p<32; p+=NSUB){
    int n = n0 + p;
    float d = dd[((long)b*NP + n)*O + o];
    const int* ip = idx + ((long)b*NP + n)*KK;
    float m = -__builtin_inff(), mm = __builtin_inff(), s = 0.f, s2 = 0.f;
    #pragma unroll
    for(int k=0;k<KK;k++){
      int j = ip[k];
      float v = yab[(long)j*O + o] + d;
      s += v; s2 += v*v;
      m = fmaxf(m, v); mm = fminf(mm, v);
    }
    mx[((long)b*NP + n)*O + o] = m;
    mn[((long)b*NP + n)*O + o] = mm;
    gs += s; gs2 += s2;
  }
  #pragma unroll
  for(int offm=1; offm<CPG; offm<<=1){
    gs  += __shfl_xor(gs,  offm, CPG);
    gs2 += __shfl_xor(gs2, offm, CPG);
  }
  if ((o & (CPG-1)) == 0){
    int g = o / CPG;
    sred2[w][g*2]   = gs;
    sred2[w][g*2+1] = gs2;
  }
  __syncthreads();
  if (t < 16){
    float a = sred2[0][t] + sred2[1][t] + sred2[2][t] + sred2[3][t];
    atomicAdd(&stats[b*16 + t], a);
  }
}

// ---------------- edge normalize (+leaky) -> bf16 mirrors only ----------------
template<int O, bool NEEDXX, bool WRITEL>
__global__ __launch_bounds__(256) void enorm_kernel(const float* __restrict__ mx, const float* __restrict__ mn,
                                                    const float* __restrict__ stats,
                                                    const float* __restrict__ gw, const float* __restrict__ gb,
                                                    int coff,
                                                    float* __restrict__ xxout,
                                                    unsigned* __restrict__ fhout, unsigned* __restrict__ flout){
  __shared__ float lmx[64][65];
  __shared__ float lmn[64][65];
  const int b = blockIdx.z;
  const int o0 = blockIdx.y*64;
  const int n0 = blockIdx.x*64;
  const int t = threadIdx.x;
  for(int r=0;r<16;r++){
    int i = r*4 + t/64, j = t%64;
    long src = ((long)b*NP + n0 + i)*O + o0 + j;
    lmx[i][j] = mx[src];
    lmn[i][j] = mn[src];
  }
  __syncthreads();
  constexpr int CPG = O/8;
  const float inv_cnt = 1.f/((float)CPG*NP*KK);
  float xacc = 0.f;
  for(int r=0;r<16;r++){
    int ol = r*4 + t/64, nl = t%64;
    int og = o0 + ol;
    int g = og / CPG;
    float S  = stats[(b*8+g)*2];
    float S2 = stats[(b*8+g)*2+1];
    float mu = S*inv_cnt;
    float var = S2*inv_cnt - mu*mu;
    float rs = rsqrtf(var + EPSV);
    float w = gw[og], bb = gb[og];
    float sel = (w >= 0.f) ? lmx[nl][ol] : lmn[nl][ol];
    float v = leakyf((sel - mu)*rs*w + bb);
    lmx[nl][ol] = v;
    if (NEEDXX) xacc += v*v;
  }
  __syncthreads();
  {
    const int cb2 = (coff + o0) >> 1;
    #pragma unroll
    for(int k=0;k<8;k++){
      int flat = k*256 + t;
      int n = flat >> 5, cp = flat & 31;
      float v0 = lmx[n][2*cp], v1 = lmx[n][2*cp+1];
      unsigned short h0 = b16(v0), h1 = b16(v1);
      fhout[((long)b*NP + n0 + n)*128 + cb2 + cp] = (unsigned)h0 | ((unsigned)h1<<16);
      if (WRITEL){
        float r0 = v0 - __uint_as_float(((unsigned)h0)<<16);
        float r1 = v1 - __uint_as_float(((unsigned)h1)<<16);
        flout[((long)b*NP + n0 + n)*64 + cb2 + cp] =
            (unsigned)b16(r0) | ((unsigned)b16(r1)<<16);
      }
    }
  }
  if (NEEDXX){
    __syncthreads();
    float* red = &lmn[0][0];
    red[(t>>6)*64 + (t&63)] = xacc;
    __syncthreads();
    if (t < 64){
      float a = red[t] + red[64+t] + red[128+t] + red[192+t];
      xxout[b*NP + n0 + t] = a;
    }
  }
}

// ---------------- MFMA bf16 GEMM; XBF16: W and X staged from bf16 mirrors (pure copies) ----------------
template<bool WRITE_Y, bool DO_STATS, bool DO_MAXMIN, bool IN_NORM, bool XBF16>
__global__ __launch_bounds__(256) void mgemm_kernel(
    const float* __restrict__ W, int ldw,
    const float* __restrict__ x, long xldb,
    const unsigned short* __restrict__ xbf,
    const unsigned short* __restrict__ wbf,
    const float* __restrict__ bias, const float* __restrict__ basev,
    int O, int C, int gshift,
    float* __restrict__ y, float* __restrict__ stats,
    unsigned* __restrict__ mmax, unsigned* __restrict__ mmin,
    const float* __restrict__ instats, const float* __restrict__ igw,
    const float* __restrict__ igb, int igshift, float iinv)
{
  constexpr int SMB = XBF16 ? 128*136 : 128*80;
  __shared__ __align__(16) char SA[SMB];
  __shared__ __align__(16) char SB[SMB];
  __shared__ float sred[16];
  __shared__ unsigned smax[128];
  __shared__ unsigned smin[128];

  const int b  = blockIdx.z;
  const int o0 = blockIdx.y*128;
  const int nb = blockIdx.x*128;
  const int t  = threadIdx.x;
  const int lane = t & 63;
  const int wid = t >> 6;
  const int wmo = wid >> 1, wno = wid & 1;
  const int lr = lane & 15, lg = lane >> 4;

  if (DO_STATS && t < 16) sred[t] = 0.f;
  if (DO_MAXMIN && t < 128){ smax[t] = 0u; smin[t] = 0xFFFFFFFFu; }

  f32x4 acc[4][4];
  #pragma unroll
  for(int i=0;i<4;i++)
    #pragma unroll
    for(int j=0;j<4;j++) acc[i][j] = (f32x4){0.f,0.f,0.f,0.f};

  if (XBF16){
    // WT/XT: ushort [128][68] rows (knnf layout, measured conflict-free)
    unsigned short (*WT)[68] = (unsigned short(*)[68])SA;
    unsigned short (*XT)[68] = (unsigned short(*)[68])SB;
    #define STAGEM(cc_)                                                                     \
      {                                                                                     \
        const int cc__ = (cc_);                                                             \
        _Pragma("unroll")                                                                   \
        for(int i = t; i < 512; i += 256){                                                  \
          int row = i >> 2, seg = i & 3;                                                    \
          *(uint4*)&WT[row][seg*8] = *(const uint4*)(wbf + (long)(o0+row)*256 + cc__ + seg*8); \
          *(uint4*)&XT[row][seg*8] = *(const uint4*)(xbf + ((long)b*NP + nb + row)*256 + cc__ + seg*8); \
        }                                                                                   \
      }
    STAGEM(0);
    for(int cc=0; cc<C; cc+=32){
      __syncthreads();
      bf16x8 afr[4], bfr[4];
      #pragma unroll
      for(int mi=0;mi<4;mi++) afr[mi] = *(const bf16x8*)&WT[wmo*64 + mi*16 + lr][lg*8];
      #pragma unroll
      for(int nj=0;nj<4;nj++) bfr[nj] = *(const bf16x8*)&XT[wno*64 + nj*16 + lr][lg*8];
      #pragma unroll
      for(int mi=0;mi<4;mi++)
        #pragma unroll
        for(int nj=0;nj<4;nj++)
          acc[mi][nj] = __builtin_amdgcn_mfma_f32_16x16x32_bf16(afr[mi], bfr[nj], acc[mi][nj], 0, 0, 0);
      __syncthreads();
      if (cc + 32 < C){ STAGEM(cc + 32); }
    }
    #undef STAGEM
  } else {
    const int so  = t & 127;
    const int scb = (t >> 7) << 5;
    const int xcg = t >> 5;
    const int xng = t & 31;
    for(int cc=0; cc<C; cc+=32){
      __syncthreads();
      {
        const float* wp = W + (long)(o0 + so)*ldw + cc + (scb>>1);
        #pragma unroll
        for(int j=0;j<4;j++){
          float4 f = *(const float4*)(wp + j*4);
          uint2 v = { bf2(f.x,f.y), bf2(f.z,f.w) };
          *(uint2*)ldsW(SA, so, scb + j*8) = v;
        }
      }
      {
        const float* xp = x + (long)b*xldb + (long)(cc + xcg*4)*NP + nb + xng*4;
        float4 f0 = *(const float4*)(xp);
        float4 f1 = *(const float4*)(xp + NP);
        float4 f2 = *(const float4*)(xp + 2*NP);
        float4 f3 = *(const float4*)(xp + 3*NP);
        float X4[4][4] = {{f0.x,f0.y,f0.z,f0.w},{f1.x,f1.y,f1.z,f1.w},
                          {f2.x,f2.y,f2.z,f2.w},{f3.x,f3.y,f3.z,f3.w}};
        if (IN_NORM){
          #pragma unroll
          for(int i=0;i<4;i++){
            int c = cc + xcg*4 + i;
            int g = c >> igshift;
            const float* sp = instats + ((long)b*(C>>igshift) + g)*2;
            float mu = sp[0]*iinv;
            float var = sp[1]*iinv - mu*mu;
            float rs = rsqrtf(var + EPSV);
            float aa = rs*igw[c];
            float c2 = igb[c] - mu*aa;
            #pragma unroll
            for(int j=0;j<4;j++) X4[i][j] = fmaxf(X4[i][j]*aa + c2, 0.f);
          }
        }
        #pragma unroll
        for(int j=0;j<4;j++){
          uint2 v = { bf2(X4[0][j], X4[1][j]), bf2(X4[2][j], X4[3][j]) };
          *(uint2*)ldsX(SB, xng*4 + j, xcg*8) = v;
        }
      }
      __syncthreads();
      bf16x8 afr[4], bfr[4];
      #pragma unroll
      for(int mi=0;mi<4;mi++) afr[mi] = *(const bf16x8*)ldsW(SA, wmo*64 + mi*16 + lr, lg*16);
      #pragma unroll
      for(int nj=0;nj<4;nj++) bfr[nj] = *(const bf16x8*)ldsX(SB, wno*64 + nj*16 + lr, lg*16);
      #pragma unroll
      for(int mi=0;mi<4;mi++)
        #pragma unroll
        for(int nj=0;nj<4;nj++)
          acc[mi][nj] = __builtin_amdgcn_mfma_f32_16x16x32_bf16(afr[mi], bfr[nj], acc[mi][nj], 0, 0, 0);
    }
  }

  float bb4[4][4];
  #pragma unroll
  for(int mi=0;mi<4;mi++){
    #pragma unroll
    for(int r=0;r<4;r++){
      int o = o0 + wmo*64 + mi*16 + lg*4 + r;
      float v = 0.f;
      if (bias)  v += bias[o];
      if (basev) v += basev[(long)b*O + o];
      bb4[mi][r] = v;
    }
  }
  #pragma unroll
  for(int mi=0;mi<4;mi++)
    #pragma unroll
    for(int nj=0;nj<4;nj++)
      #pragma unroll
      for(int r=0;r<4;r++) acc[mi][nj][r] += bb4[mi][r];

  if (WRITE_Y){
    #pragma unroll
    for(int mi=0;mi<4;mi++)
      #pragma unroll
      for(int nj=0;nj<4;nj++)
        #pragma unroll
        for(int r=0;r<4;r++){
          int o = o0 + wmo*64 + mi*16 + lg*4 + r;
          y[((long)b*O + o)*NP + nb + wno*64 + nj*16 + lr] = acc[mi][nj][r];
        }
  }
  if (DO_STATS){
    #pragma unroll
    for(int mi=0;mi<4;mi++){
      float s = 0.f, s2 = 0.f;
      #pragma unroll
      for(int nj=0;nj<4;nj++)
        #pragma unroll
        for(int r=0;r<4;r++){ float v = acc[mi][nj][r]; s += v; s2 += v*v; }
      int gi = (wmo*64 + mi*16) >> gshift;
      atomicAdd(&sred[gi*2],   s);
      atomicAdd(&sred[gi*2+1], s2);
    }
  }
  if (DO_MAXMIN){
    #pragma unroll
    for(int mi=0;mi<4;mi++)
      #pragma unroll
      for(int r=0;r<4;r++){
        float mv = acc[mi][0][r], mw = acc[mi][0][r];
        #pragma unroll
        for(int nj=1;nj<4;nj++){ mv = fmaxf(mv, acc[mi][nj][r]); mw = fminf(mw, acc[mi][nj][r]); }
        int ol = wmo*64 + mi*16 + lg*4 + r;
        atomicMax(&smax[ol], fenc(mv));
        atomicMin(&smin[ol], fenc(mw));
      }
  }
  if (DO_STATS || DO_MAXMIN) __syncthreads();
  if (DO_STATS){
    int ngb = 128 >> gshift;
    if (t < ngb*2){
      atomicAdd(&stats[((long)b*(O>>gshift) + (o0>>gshift) + (t>>1))*2 + (t&1)], sred[t]);
    }
  }
  if (DO_MAXMIN){
    if (t < 128){
      atomicMax(&mmax[(long)b*O + o0 + t], smax[t]);
      atomicMin(&mmin[(long)b*O + o0 + t], smin[t]);
    }
  }
}

// ---------------- xmax = relu(gn(max/min over n)) ----------------
__global__ void xmax_kernel(const unsigned* __restrict__ mmax, const unsigned* __restrict__ mmin,
                            const float* __restrict__ stats, const float* __restrict__ gw,
                            const float* __restrict__ gb, float* __restrict__ xmax){
  int t = blockIdx.x*256 + threadIdx.x;
  int b = t >> 10, o = t & 1023;
  int g = o >> 5;
  const float* sp = stats + (b*32+g)*2;
  const float inv_cnt = 1.f/(32.f*NP);
  float mu = sp[0]*inv_cnt;
  float var = sp[1]*inv_cnt - mu*mu;
  float rs = rsqrtf(var + EPSV);
  float w = gw[o];
  float sel = (w >= 0.f) ? fdec(mmax[t]) : fdec(mmin[t]);
  float v = (sel - mu)*rs*w + gb[o];
  xmax[t] = fmaxf(v, 0.f);
}

// ---------------- base1[b,o] = bs1[o] + Ws1[:, :1024] @ xmax[b] ----------------
__global__ __launch_bounds__(256) void base1_kernel(const float* __restrict__ Ws1, const float* __restrict__ bs1,
                                                    const float* __restrict__ xmax, float* __restrict__ base1){
  __shared__ float sred[4][8];
  const int o = blockIdx.x;
  const int t = threadIdx.x;
  const float* wp = Ws1 + (long)o*1280;
  float acc[8];
  #pragma unroll
  for(int bb=0;bb<8;bb++) acc[bb]=0.f;
  #pragma unroll
  for(int cc=0;cc<4;cc++){
    int c = cc*256 + t;
    float w = wp[c];
    #pragma unroll
    for(int bb=0;bb<8;bb++) acc[bb] += w * xmax[bb*1024 + c];
  }
  #pragma unroll
  for(int bb=0;bb<8;bb++){
    float a = acc[bb];
    a += __shfl_xor(a,1);  a += __shfl_xor(a,2);  a += __shfl_xor(a,4);
    a += __shfl_xor(a,8);  a += __shfl_xor(a,16); a += __shfl_xor(a,32);
    acc[bb]=a;
  }
  if ((t&63)==0){
    #pragma unroll
    for(int bb=0;bb<8;bb++) sred[t>>6][bb]=acc[bb];
  }
  __syncthreads();
  if (t<8){
    float a = sred[0][t]+sred[1][t]+sred[2][t]+sred[3][t] + bs1[o];
    base1[t*512 + o] = a;
  }
}

// ---------------- final: fused GN3+relu + 50-class conv + log_softmax ----------------
__global__ __launch_bounds__(256) void s4_kernel(const float* __restrict__ h3raw,
                                                 const float* __restrict__ stats,
                                                 const float* __restrict__ gw, const float* __restrict__ gb,
                                                 const float* __restrict__ W,
                                                 const float* __restrict__ bias,
                                                 float* __restrict__ out){
  const int b = blockIdx.y;
  const int n = blockIdx.x*64 + (threadIdx.x>>2);
  const int cl = threadIdx.x & 3;
  const float inv_cnt = 1.f/(16.f*NP);
  float mu0, rs0, mu1, rs1;
  {
    const float* sp = stats + (b*8 + cl*2)*2;
    mu0 = sp[0]*inv_cnt;
    float var = sp[1]*inv_cnt - mu0*mu0;
    rs0 = rsqrtf(var + EPSV);
    const float* sp1 = stats + (b*8 + cl*2 + 1)*2;
    mu1 = sp1[0]*inv_cnt;
    float var1 = sp1[1]*inv_cnt - mu1*mu1;
    rs1 = rsqrtf(var1 + EPSV);
  }
  float hv[32];
  #pragma unroll
  for(int c=0;c<32;c++){
    int og = cl*32 + c;
    float rs = (c < 16) ? rs0 : rs1;
    float mu = (c < 16) ? mu0 : mu1;
    float a = rs*gw[og];
    float c2 = gb[og] - mu*a;
    float v = h3raw[((long)b*128 + og)*NP + n];
    hv[c] = fmaxf(v*a + c2, 0.f);
  }
  float zz[50];
  #pragma unroll
  for(int o=0;o<50;o++){
    const float* wp = W + o*128 + cl*32;
    float a = 0.f;
    #pragma unroll
    for(int c=0;c<32;c++) a += wp[c]*hv[c];
    a += __shfl_xor(a,1);
    a += __shfl_xor(a,2);
    zz[o] = a + bias[o];
  }
  float m = zz[0];
  #pragma unroll
  for(int o=1;o<50;o++) m = fmaxf(m, zz[o]);
  float s = 0.f;
  #pragma unroll
  for(int o=0;o<50;o++) s += __expf(zz[o]-m);
  float lse = m + __logf(s);
  #pragma unroll
  for(int o=0;o<50;o++){
    if ((o&3)==cl) out[((long)b*50+o)*NP+n] = zz[o]-lse;
  }
}

extern "C" void kernel_launch(void* const* d_in, const int* in_sizes, int n_in,
                              void* d_out, int out_size, void* d_ws, size_t ws_size,
                              hipStream_t stream)
{
  const float* x   = (const float*)d_in[0];
  const float* W1  = (const float*)d_in[1];
  const float* W2  = (const float*)d_in[2];
  const float* W3  = (const float*)d_in[3];
  const float* g1w = (const float*)d_in[4];
  const float* g1b = (const float*)d_in[5];
  const float* g2w = (const float*)d_in[6];
  const float* g2b = (const float*)d_in[7];
  const float* g3w = (const float*)d_in[8];
  const float* g3b = (const float*)d_in[9];
  const float* gfw = (const float*)d_in[10];
  const float* gfb = (const float*)d_in[11];
  const float* gs1w= (const float*)d_in[12];
  const float* gs1b= (const float*)d_in[13];
  const float* gs2w= (const float*)d_in[14];
  const float* gs2b= (const float*)d_in[15];
  const float* gs3w= (const float*)d_in[16];
  const float* gs3b= (const float*)d_in[17];
  const float* Wm  = (const float*)d_in[18];
  const float* bm  = (const float*)d_in[19];
  const float* Ws1 = (const float*)d_in[20];
  const float* bs1 = (const float*)d_in[21];
  const float* Ws2 = (const float*)d_in[22];
  const float* bs2 = (const float*)d_in[23];
  const float* Ws3 = (const float*)d_in[24];
  const float* bs3 = (const float*)d_in[25];
  const float* Ws4 = (const float*)d_in[26];
  const float* bs4 = (const float*)d_in[27];
  float* out = (float*)d_out;

  char* ws = (char*)d_ws;
  size_t off = 0;
  auto alloc = [&](size_t bytes)->char*{
    char* p = ws + off;
    off += (bytes + 255) & ~(size_t)255;
    return p;
  };
  char* zbase = alloc(6656 + 32768);
  float* estats1 = (float*)(zbase + 0);
  float* estats2 = (float*)(zbase + 512);
  float* estats3 = (float*)(zbase + 1024);
  float* mstats  = (float*)(zbase + 1536);
  float* s1stats = (float*)(zbase + 3584);
  float* s2stats = (float*)(zbase + 4608);
  float* s3stats = (float*)(zbase + 5632);
  unsigned* mmax = (unsigned*)(zbase + 6656);
  unsigned* mmin = (unsigned*)alloc(32768);
  float* xmaxb = (float*)alloc(8*1024*4);
  float* base1 = (float*)alloc(8*512*4);
  int*   idxb  = (int*)  alloc((size_t)BN*NP*KK*4);
  float* xxb   = (float*)alloc((size_t)BN*NP*4);
  unsigned short* wmb  = (unsigned short*)alloc((size_t)1024*256*2);
  unsigned short* ws1b = (unsigned short*)alloc((size_t)512*256*2);
  unsigned* fhb = (unsigned*)alloc((size_t)BN*NP*256*2);
  unsigned* flb = (unsigned*)alloc((size_t)BN*NP*128*2);
  float* ya    = (float*)alloc((size_t)BN*NP*128*4);
  float* dd    = (float*)alloc((size_t)BN*NP*128*4);
  float* mx    = (float*)alloc((size_t)BN*NP*128*4);
  float* mn    = (float*)alloc((size_t)BN*NP*128*4);
  float* ybuf1 = (float*)alloc((size_t)BN*512*NP*4);
  float* ybuf2 = (float*)alloc((size_t)BN*256*NP*4);
  float* ybuf3 = (float*)alloc((size_t)BN*128*NP*4);

  // pk (41.9MB) aliases ya..mn — consumers strictly ordered after merge.
  unsigned* pk = (unsigned*)ya;
  const unsigned short* fh16 = (const unsigned short*)fhb;
  const unsigned short* fl16 = (const unsigned short*)flb;

  hipMemsetAsync(zbase, 0, 6656 + 32768, stream);
  hipMemsetAsync(mmin, 0xFF, 32768, stream);

  dim3 blk256(256);

  // ---- one-time weight bf16 mirrors ----
  wprep_kernel<<<dim3(1024), blk256, 0, stream>>>(Wm, 256, 1024, wmb);
  wprep_kernel<<<dim3(512),  blk256, 0, stream>>>(Ws1 + 1024, 1280, 512, ws1b);

  // ---- edge block 1 (C=3 -> 64, mirror cols [0,64)) ----
  xx_kernel<<<dim3(NP/256, BN), blk256, 0, stream>>>(x, (long)3*NP, 3, xxb);
  knn1_kernel<<<dim3(NP/64, 8, BN), blk256, 0, stream>>>(x, xxb, pk);
  knnmerge_kernel<<<dim3(BN*NP/4), blk256, 0, stream>>>(pk, idxb);
  pcdual_kernel<3,64><<<dim3(NP/4, BN), blk256, 0, stream>>>(x, (long)3*NP, W1, ya, dd);
  egather_kernel<64><<<dim3(8*NP/32), blk256, 0, stream>>>(ya, dd, idxb, mx, mn, estats1);
  enorm_kernel<64,true,true><<<dim3(NP/64, 1, BN), blk256, 0, stream>>>(
      mx, mn, estats1, g1w, g1b, 0, xxb, fhb, flb);

  // ---- edge block 2 (C=64 -> 64, in cols [0,64), out cols [64,128)) ----
  knnf_kernel<<<dim3(NP/64, 8, BN), blk256, 0, stream>>>(fh16, fl16, 0, xxb, pk);
  knnmerge_kernel<<<dim3(BN*NP/4), blk256, 0, stream>>>(pk, idxb);
  pcdualm_kernel<64><<<dim3(NP/64, BN), blk256, 0, stream>>>(fh16, fl16, 0, W2, ya, dd);
  egather_kernel<64><<<dim3(8*NP/32), blk256, 0, stream>>>(ya, dd, idxb, mx, mn, estats2);
  enorm_kernel<64,true,true><<<dim3(NP/64, 1, BN), blk256, 0, stream>>>(
      mx, mn, estats2, g2w, g2b, 64, xxb, fhb, flb);

  // ---- edge block 3 (C=64 -> 128, in cols [64,128), out cols [128,256) hi-only) ----
  knnf_kernel<<<dim3(NP/64, 8, BN), blk256, 0, stream>>>(fh16, fl16, 64, xxb, pk);
  knnmerge_kernel<<<dim3(BN*NP/4), blk256, 0, stream>>>(pk, idxb);
  pcdualm_kernel<128><<<dim3(NP/64, BN), blk256, 0, stream>>>(fh16, fl16, 64, W3, ya, dd);
  egather_kernel<128><<<dim3(8*NP/32), blk256, 0, stream>>>(ya, dd, idxb, mx, mn, estats3);
  enorm_kernel<128,false,false><<<dim3(NP/64, 2, BN), blk256, 0, stream>>>(
      mx, mn, estats3, g3w, g3b, 128, nullptr, fhb, nullptr);

  // ---- global conv (Wm 1024x256): W+X staged from bf16 mirrors ----
  mgemm_kernel<false,true,true,false,true><<<dim3(16,8,BN), blk256, 0, stream>>>(
      nullptr, 0, nullptr, 0, fh16, wmb, bm, nullptr, 1024, 256, 5,
      nullptr, mstats, mmax, mmin, nullptr, nullptr, nullptr, 0, 0.f);
  xmax_kernel<<<dim3(32), blk256, 0, stream>>>(mmax, mmin, mstats, gfw, gfb, xmaxb);
  base1_kernel<<<dim3(512), blk256, 0, stream>>>(Ws1, bs1, xmaxb, base1);

  // ---- seg conv 1: W+X staged from bf16 mirrors ----
  mgemm_kernel<true,true,false,false,true><<<dim3(16,4,BN), blk256, 0, stream>>>(
      nullptr, 0, nullptr, 0, fh16, ws1b, nullptr, base1, 512, 256, 5,
      ybuf1, s1stats, nullptr, nullptr, nullptr, nullptr, nullptr, 0, 0.f);

  // ---- seg conv 2 (fused GN1+relu on fp32 input) ----
  mgemm_kernel<true,true,false,true,false><<<dim3(16,2,BN), blk256, 0, stream>>>(
      Ws2, 512, ybuf1, (long)512*NP, nullptr, nullptr, bs2, nullptr, 256, 512, 4,
      ybuf2, s2stats, nullptr, nullptr, s1stats, gs1w, gs1b, 5, 1.f/(32.f*NP));

  // ---- seg conv 3 (fused GN2+relu on fp32 input) ----
  mgemm_kernel<true,true,false,true,false><<<dim3(16,1,BN), blk256, 0, stream>>>(
      Ws3, 256, ybuf2, (long)256*NP, nullptr, nullptr, bs3, nullptr, 128, 256, 4,
      ybuf3, s3stats, nullptr, nullptr, s2stats, gs2w, gs2b, 4, 1.f/(16.f*NP));

  // ---- final: fused GN3+relu + conv + log_softmax ----
  s4_kernel<<<dim3(NP/64, BN), blk256, 0, stream>>>(ybuf3, s3stats, gs3w, gs3b, Ws4, bs4, out);
}

// Round 19
// 536.178 us; speedup vs baseline: 1.0646x; 1.0646x over previous
//
#include <hip/hip_runtime.h>

#define BN 8
#define NP 2048
#define KK 20
#define EPSV 1e-5f

typedef __attribute__((ext_vector_type(8))) short bf16x8;
typedef __attribute__((ext_vector_type(4))) float f32x4;

static __device__ __forceinline__ float leakyf(float v){ return v >= 0.f ? v : 0.2f*v; }
static __device__ __forceinline__ unsigned fenc(float f){
  unsigned u = __float_as_uint(f);
  unsigned m = (unsigned)((int)u >> 31);
  return u ^ (m | 0x80000000u);
}
static __device__ __forceinline__ float fdec(unsigned u){
  return __uint_as_float((u & 0x80000000u) ? (u & 0x7FFFFFFFu) : ~u);
}
static __device__ __forceinline__ unsigned bf2(float a, float b){
  unsigned ua = __float_as_uint(a), ub = __float_as_uint(b);
  ua = (ua + 0x7FFFu + ((ua>>16)&1u)) >> 16;
  ub = (ub + 0x7FFFu + ((ub>>16)&1u)) >> 16;
  return ua | (ub<<16);
}
static __device__ __forceinline__ unsigned short b16(float v){
  unsigned u = __float_as_uint(v);
  return (unsigned short)((u + 0x7FFFu + ((u>>16)&1u)) >> 16);
}
static __device__ __forceinline__ unsigned umax32(unsigned a, unsigned b){ return __builtin_elementwise_max(a,b); }
static __device__ __forceinline__ unsigned med3u(unsigned a, unsigned b, unsigned c){
  unsigned d;
  asm("v_med3_u32 %0, %1, %2, %3" : "=v"(d) : "v"(a), "v"(b), "v"(c));
  return d;
}

// LDS addressing for mgemm: 80B rows, XOR swizzle on bits 4-5.
static __device__ __forceinline__ char* ldsW(char* base, int row, int colb){
  return base + row*80 + (colb ^ ((((unsigned)row>>3)&3u)<<4));
}
static __device__ __forceinline__ char* ldsX(char* base, int row, int colb){
  return base + row*80 + (colb ^ (((((unsigned)row>>2)^((unsigned)row>>4))&3u)<<4));
}
static __device__ __forceinline__ int swz128(int row, int colb){
  return (colb ^ ((row&7)<<4));
}

// ---------------- xx = sum_c x^2 (block1 only, on raw x) ----------------
__global__ __launch_bounds__(256) void xx_kernel(const float* __restrict__ x, long ldb, int C,
                                                 float* __restrict__ xx){
  int b = blockIdx.y;
  int n = blockIdx.x*256 + threadIdx.x;
  const float* xp = x + (long)b*ldb + n;
  float a = 0.f;
  for(int c=0;c<C;c++){ float v = xp[(long)c*NP]; a += v*v; }
  xx[b*NP + n] = a;
}

// ---------------- branch-free u32 key insert: 1 med3 per position ----------------
static __device__ __forceinline__ void ins20(unsigned* tv, unsigned key){
  unsigned pold = tv[0];
  tv[0] = umax32(tv[0], key);
  #pragma unroll
  for(int r=1;r<20;r++){
    unsigned cold = tv[r];
    tv[r] = med3u(key, pold, cold);
    pold = cold;
  }
}

// ---------------- knn C=64 v4: candidates cooperatively staged in LDS ----------------
__global__ __launch_bounds__(256) void knnf_kernel(const unsigned short* __restrict__ fh,
                                                   const unsigned short* __restrict__ fl,
                                                   const float* __restrict__ xx,
                                                   unsigned* __restrict__ pk){
  __shared__ unsigned short CH[64][68];
  __shared__ unsigned short CL[64][68];
  __shared__ unsigned SK[64][68];
  __shared__ float cxs[64];
  const int b    = blockIdx.z;
  const int part = blockIdx.y;
  const int q0   = blockIdx.x*64;
  const int t    = threadIdx.x;
  const int lane = t & 63;
  const int w    = t >> 6;
  const int lr   = lane & 15, lg = lane >> 4;
  const unsigned short* fhb = fh + (long)b*NP*64;
  const unsigned short* flb = fl + (long)b*NP*64;
  const float* xxb = xx + b*NP;

  const unsigned short* qa = fhb + ((long)(q0 + w*16 + lr))*64 + lg*8;
  const unsigned short* qb = flb + ((long)(q0 + w*16 + lr))*64 + lg*8;
  bf16x8 ah0 = *(const bf16x8*)(qa);
  bf16x8 ah1 = *(const bf16x8*)(qa + 32);
  bf16x8 al0 = *(const bf16x8*)(qb);
  bf16x8 al1 = *(const bf16x8*)(qb + 32);
  float4 qxx4 = *(const float4*)(xxb + q0 + w*16 + lg*4);
  float qxx[4] = {qxx4.x, qxx4.y, qxx4.z, qxx4.w};

  unsigned tv[20];
  #pragma unroll
  for(int r=0;r<20;r++) tv[r] = 0u;
  const int sq = t>>2, sl = t&3;

  #define STAGE(ct_)                                                                  \
    {                                                                                 \
      const int ct__ = (ct_);                                                         \
      _Pragma("unroll")                                                               \
      for(int i = t; i < 512; i += 256){                                              \
        int row = i >> 3, seg = i & 7;                                                \
        *(uint4*)&CH[row][seg*8] = *(const uint4*)(fhb + ((long)(ct__*64+row))*64 + seg*8); \
        *(uint4*)&CL[row][seg*8] = *(const uint4*)(flb + ((long)(ct__*64+row))*64 + seg*8); \
      }                                                                               \
      if (t < 64) cxs[t] = xxb[ct__*64 + t];                                          \
    }

  STAGE(part*4);
  __syncthreads();

  #pragma unroll
  for(int cc=0; cc<4; cc++){
    __builtin_amdgcn_s_setprio(1);
    f32x4 acc[4];
    #pragma unroll
    for(int nt=0; nt<4; nt++){
      int crow = nt*16 + lr;
      bf16x8 bh0 = *(const bf16x8*)&CH[crow][lg*8];
      bf16x8 bh1 = *(const bf16x8*)&CH[crow][32 + lg*8];
      bf16x8 bl0 = *(const bf16x8*)&CL[crow][lg*8];
      bf16x8 bl1 = *(const bf16x8*)&CL[crow][32 + lg*8];
      f32x4 a = (f32x4){0.f,0.f,0.f,0.f};
      a = __builtin_amdgcn_mfma_f32_16x16x32_bf16(ah0, bh0, a, 0,0,0);
      a = __builtin_amdgcn_mfma_f32_16x16x32_bf16(ah1, bh1, a, 0,0,0);
      a = __builtin_amdgcn_mfma_f32_16x16x32_bf16(ah0, bl0, a, 0,0,0);
      a = __builtin_amdgcn_mfma_f32_16x16x32_bf16(ah1, bl1, a, 0,0,0);
      a = __builtin_amdgcn_mfma_f32_16x16x32_bf16(al0, bh0, a, 0,0,0);
      a = __builtin_amdgcn_mfma_f32_16x16x32_bf16(al1, bh1, a, 0,0,0);
      acc[nt] = a;
    }
    __builtin_amdgcn_s_setprio(0);
    float cxv[4];
    #pragma unroll
    for(int nt=0; nt<4; nt++) cxv[nt] = cxs[nt*16 + lr];
    unsigned key4[4][4];
    #pragma unroll
    for(int nt=0; nt<4; nt++){
      #pragma unroll
      for(int r=0;r<4;r++){
        float neg = 2.f*acc[nt][r] - qxx[r] - cxv[nt];
        key4[nt][r] = (fenc(neg) & 0xFFFFFF00u) | (255u - (unsigned)(cc*64 + nt*16 + lr));
      }
    }
    __syncthreads();
    #pragma unroll
    for(int nt=0; nt<4; nt++)
      #pragma unroll
      for(int r=0;r<4;r++)
        SK[w*16 + lg*4 + r][nt*16 + lr] = key4[nt][r];
    if (cc < 3){
      STAGE(part*4 + cc + 1);
    }
    __syncthreads();
    #pragma unroll
    for(int jj=0;jj<4;jj++){
      uint4 kv = *(const uint4*)&SK[sq][sl*16 + jj*4];
      ins20(tv, kv.x); ins20(tv, kv.y); ins20(tv, kv.z); ins20(tv, kv.w);
    }
  }
  #undef STAGE
  long base = ((((long)b*NP + q0 + sq)*8 + part)*4 + sl)*20;
  #pragma unroll
  for(int r=0;r<20;r++) pk[base+r] = tv[r];
}

// ---------------- knn C=3 direct ----------------
__global__ __launch_bounds__(256) void knn1_kernel(const float* __restrict__ x,
                                                   const float* __restrict__ xx,
                                                   unsigned* __restrict__ pk){
  __shared__ float cx0[256], cx1[256], cx2[256], cxxa[256];
  const int b    = blockIdx.z;
  const int part = blockIdx.y;
  const int q0   = blockIdx.x*64;
  const int t    = threadIdx.x;
  const float* xb  = x + (long)b*3*NP;
  const float* xxb = xx + b*NP;

  cx0[t]  = xb[part*256 + t];
  cx1[t]  = xb[NP + part*256 + t];
  cx2[t]  = xb[2*NP + part*256 + t];
  cxxa[t] = xxb[part*256 + t];

  const int sq = t>>2, sl = t&3;
  const int q = q0 + sq;
  float qx = xb[q], qy = xb[NP + q], qz = xb[2*NP + q];
  float qxx = xxb[q];
  __syncthreads();

  unsigned tv[20];
  #pragma unroll
  for(int r=0;r<20;r++) tv[r] = 0u;

  for(int cc=0; cc<4; cc++){
    #pragma unroll
    for(int j=0;j<16;j++){
      int m = cc*64 + sl*16 + j;
      float ip = qx*cx0[m] + qy*cx1[m] + qz*cx2[m];
      float neg = 2.f*ip - qxx - cxxa[m];
      unsigned key = (fenc(neg) & 0xFFFFFF00u) | (255u - (unsigned)m);
      ins20(tv, key);
    }
  }
  long base = ((((long)b*NP + q0 + sq)*8 + part)*4 + sl)*20;
  #pragma unroll
  for(int r=0;r<20;r++) pk[base+r] = tv[r];
}

// ---------------- wave-parallel merge ----------------
__global__ __launch_bounds__(256) void knnmerge_kernel(const unsigned* __restrict__ pk,
                                                       int* __restrict__ idxout){
  const int wid  = threadIdx.x >> 6;
  const int lane = threadIdx.x & 63;
  const long qg = (long)blockIdx.x*4 + wid;
  const unsigned* kb = pk + qg*640;
  const int l = lane >> 1, h = lane & 1;
  unsigned k[10];
  {
    const unsigned* src = kb + l*20 + h*10;
    #pragma unroll
    for(int i=0;i<10;i++) k[i] = src[i];
  }
  int rem = 10;
  int* op = idxout + qg*KK;
  const int gbase = (l>>2)*256;
  for(int r=0;r<KK;r++){
    unsigned key = k[0];
    int gi = gbase + 255 - (int)(key & 255u);
    unsigned long long cmp = (rem > 0)
        ? ((unsigned long long)(key & 0xFFFFFF00u) << 32) | (unsigned)(0x7FFFFFFF - gi)
        : 0ull;
    unsigned long long w = cmp;
    #pragma unroll
    for(int s=1;s<64;s<<=1){
      unsigned long long o = __shfl_xor(w, s, 64);
      w = (o > w) ? o : w;
    }
    if (lane == 0){
      op[r] = 0x7FFFFFFF - (int)(unsigned)(w & 0xFFFFFFFFu);
    }
    if (cmp == w){
      #pragma unroll
      for(int i=0;i<9;i++) k[i] = k[i+1];
      rem--;
    }
  }
}

// ---------------- edge conv C=3: vector ----------------
template<int CIN, int O>
__global__ __launch_bounds__(256) void pcdual_kernel(const float* __restrict__ x, long ldb,
                                                     const float* __restrict__ W,
                                                     float* __restrict__ ya, float* __restrict__ dd){
  __shared__ float Wt[CIN][O+1];
  constexpr int NLOC = 256/O;
  const int b = blockIdx.y;
  const int n0 = blockIdx.x*NLOC;
  const int t = threadIdx.x;
  const int o = t % O;
  const int n = n0 + t/O;
  const float* xp = x + (long)b*ldb + n;
  float xv[CIN];
  #pragma unroll
  for(int c=0;c<CIN;c++) xv[c] = xp[(long)c*NP];
  for(int i=t;i<CIN*O;i+=256){ int oo=i/CIN, c=i%CIN; Wt[c][oo] = W[(long)oo*2*CIN + c]; }
  __syncthreads();
  float aa = 0.f;
  #pragma unroll
  for(int c=0;c<CIN;c++) aa += Wt[c][o]*xv[c];
  __syncthreads();
  for(int i=t;i<CIN*O;i+=256){ int oo=i/CIN, c=i%CIN; Wt[c][oo] = W[(long)oo*2*CIN + CIN + c]; }
  __syncthreads();
  float ab = 0.f;
  #pragma unroll
  for(int c=0;c<CIN;c++) ab += Wt[c][o]*xv[c];
  long outoff = ((long)b*NP + n)*O + o;
  ya[outoff] = aa;
  dd[outoff] = ab - aa;
}

// ---------------- edge conv C=64 via MFMA from bf16 hi/lo mirrors ----------------
template<int O>
__global__ __launch_bounds__(256) void pcdualm_kernel(const unsigned short* __restrict__ fh,
                                                      const unsigned short* __restrict__ fl,
                                                      const float* __restrict__ W,
                                                      float* __restrict__ ya, float* __restrict__ dd){
  __shared__ unsigned short AH[O][64];
  __shared__ unsigned short AL[O][64];
  __shared__ unsigned short DH[O][64];
  __shared__ unsigned short DL[O][64];
  const int b  = blockIdx.y;
  const int n0 = blockIdx.x*64;
  const int t  = threadIdx.x;
  const int lane = t & 63;
  const int w  = t >> 6;
  const int lr = lane & 15, lg = lane >> 4;

  for(int i=t; i<O*64; i+=256){
    int o = i >> 6, c = i & 63;
    float va = W[(long)o*128 + c];
    float vb = W[(long)o*128 + 64 + c];
    float vd = vb - va;
    unsigned short ah = b16(va);
    unsigned short dh = b16(vd);
    int byt = swz128(o, c*2);
    *(unsigned short*)((char*)&AH[o][0] + byt) = ah;
    *(unsigned short*)((char*)&AL[o][0] + byt) = b16(va - __uint_as_float(((unsigned)ah)<<16));
    *(unsigned short*)((char*)&DH[o][0] + byt) = dh;
    *(unsigned short*)((char*)&DL[o][0] + byt) = b16(vd - __uint_as_float(((unsigned)dh)<<16));
  }

  const int n = n0 + w*16 + lr;
  const unsigned short* xh = fh + ((long)b*NP + n)*64 + lg*8;
  const unsigned short* xl = fl + ((long)b*NP + n)*64 + lg*8;
  bf16x8 xh0 = *(const bf16x8*)(xh);
  bf16x8 xh1 = *(const bf16x8*)(xh + 32);
  bf16x8 xl0 = *(const bf16x8*)(xl);
  bf16x8 xl1 = *(const bf16x8*)(xl + 32);
  __syncthreads();

  #pragma unroll
  for(int mi=0; mi<O/16; mi++){
    int row = mi*16 + lr;
    bf16x8 a_h0 = *(const bf16x8*)((char*)&AH[row][0] + swz128(row, lg*16));
    bf16x8 a_h1 = *(const bf16x8*)((char*)&AH[row][0] + swz128(row, 64 + lg*16));
    bf16x8 a_l0 = *(const bf16x8*)((char*)&AL[row][0] + swz128(row, lg*16));
    bf16x8 a_l1 = *(const bf16x8*)((char*)&AL[row][0] + swz128(row, 64 + lg*16));
    f32x4 aa = (f32x4){0.f,0.f,0.f,0.f};
    aa = __builtin_amdgcn_mfma_f32_16x16x32_bf16(a_h0, xh0, aa, 0,0,0);
    aa = __builtin_amdgcn_mfma_f32_16x16x32_bf16(a_h1, xh1, aa, 0,0,0);
    aa = __builtin_amdgcn_mfma_f32_16x16x32_bf16(a_h0, xl0, aa, 0,0,0);
    aa = __builtin_amdgcn_mfma_f32_16x16x32_bf16(a_h1, xl1, aa, 0,0,0);
    aa = __builtin_amdgcn_mfma_f32_16x16x32_bf16(a_l0, xh0, aa, 0,0,0);
    aa = __builtin_amdgcn_mfma_f32_16x16x32_bf16(a_l1, xh1, aa, 0,0,0);
    bf16x8 d_h0 = *(const bf16x8*)((char*)&DH[row][0] + swz128(row, lg*16));
    bf16x8 d_h1 = *(const bf16x8*)((char*)&DH[row][0] + swz128(row, 64 + lg*16));
    bf16x8 d_l0 = *(const bf16x8*)((char*)&DL[row][0] + swz128(row, lg*16));
    bf16x8 d_l1 = *(const bf16x8*)((char*)&DL[row][0] + swz128(row, 64 + lg*16));
    f32x4 ad = (f32x4){0.f,0.f,0.f,0.f};
    ad = __builtin_amdgcn_mfma_f32_16x16x32_bf16(d_h0, xh0, ad, 0,0,0);
    ad = __builtin_amdgcn_mfma_f32_16x16x32_bf16(d_h1, xh1, ad, 0,0,0);
    ad = __builtin_amdgcn_mfma_f32_16x16x32_bf16(d_h0, xl0, ad, 0,0,0);
    ad = __builtin_amdgcn_mfma_f32_16x16x32_bf16(d_h1, xl1, ad, 0,0,0);
    ad = __builtin_amdgcn_mfma_f32_16x16x32_bf16(d_l0, xh0, ad, 0,0,0);
    ad = __builtin_amdgcn_mfma_f32_16x16x32_bf16(d_l1, xh1, ad, 0,0,0);
    long ooff = ((long)b*NP + n)*O + mi*16 + lg*4;
    float4 va = {aa[0],aa[1],aa[2],aa[3]};
    float4 vd = {ad[0],ad[1],ad[2],ad[3]};
    *(float4*)(ya + ooff) = va;
    *(float4*)(dd + ooff) = vd;
  }
}

// ---------------- edge gather v3 ----------------
template<int O>
__global__ __launch_bounds__(256) void egather_kernel(const float* __restrict__ ya, const float* __restrict__ dd,
                               const int* __restrict__ idx,
                               float* __restrict__ mx, float* __restrict__ mn,
                               float* __restrict__ stats){
  __shared__ float sred2[4][16];
  constexpr int NSUB = 256/O;
  constexpr int CPG = O/8;
  const int b  = blockIdx.x & 7;
  const int n0 = (blockIdx.x >> 3) * 32;
  const int t = threadIdx.x;
  const int w = t >> 6;
  const int o = t % O;
  const int ns = t / O;
  if (t < 64) sred2[t>>4][t&15] = 0.f;
  __syncthreads();
  float gs = 0.f, gs2 = 0.f;
  const float* yab = ya + (long)b*NP*O;
  for(int p=ns; p<32; p+=NSUB){
    int n = n0 + p;
    float d = dd[((long)b*NP + n)*O + o];
    const int* ip = idx + ((long)b*NP + n)*KK;
    float m = -__builtin_inff(), mm = __builtin_inff(), s = 0.f, s2 = 0.f;
    #pragma unroll
    for(int k=0;k<KK;k++){
      int j = ip[k];
      float v = yab[(long)j*O + o] + d;
      s += v; s2 += v*v;
      m = fmaxf(m, v); mm = fminf(mm, v);
    }
    mx[((long)b*NP + n)*O + o] = m;
    mn[((long)b*NP + n)*O + o] = mm;
    gs += s; gs2 += s2;
  }
  #pragma unroll
  for(int offm=1; offm<CPG; offm<<=1){
    gs  += __shfl_xor(gs,  offm, CPG);
    gs2 += __shfl_xor(gs2, offm, CPG);
  }
  if ((o & (CPG-1)) == 0){
    int g = o / CPG;
    sred2[w][g*2]   = gs;
    sred2[w][g*2+1] = gs2;
  }
  __syncthreads();
  if (t < 16){
    float a = sred2[0][t] + sred2[1][t] + sred2[2][t] + sred2[3][t];
    atomicAdd(&stats[b*16 + t], a);
  }
}

// ---------------- edge normalize (+leaky), transpose into feats; optional bf16 hi/lo + xx ----------------
template<int O, bool NEEDXX, bool WRITEH>
__global__ __launch_bounds__(256) void enorm_kernel(const float* __restrict__ mx, const float* __restrict__ mn,
                                                    const float* __restrict__ stats,
                                                    const float* __restrict__ gw, const float* __restrict__ gb,
                                                    float* __restrict__ feats, int coff,
                                                    float* __restrict__ xxout,
                                                    unsigned* __restrict__ fhout, unsigned* __restrict__ flout){
  __shared__ float lmx[64][65];
  __shared__ float lmn[64][65];
  const int b = blockIdx.z;
  const int o0 = blockIdx.y*64;
  const int n0 = blockIdx.x*64;
  const int t = threadIdx.x;
  for(int r=0;r<16;r++){
    int i = r*4 + t/64, j = t%64;
    long src = ((long)b*NP + n0 + i)*O + o0 + j;
    lmx[i][j] = mx[src];
    lmn[i][j] = mn[src];
  }
  __syncthreads();
  constexpr int CPG = O/8;
  const float inv_cnt = 1.f/((float)CPG*NP*KK);
  float xacc = 0.f;
  for(int r=0;r<16;r++){
    int ol = r*4 + t/64, nl = t%64;
    int og = o0 + ol;
    int g = og / CPG;
    float S  = stats[(b*8+g)*2];
    float S2 = stats[(b*8+g)*2+1];
    float mu = S*inv_cnt;
    float var = S2*inv_cnt - mu*mu;
    float rs = rsqrtf(var + EPSV);
    float w = gw[og], bb = gb[og];
    float sel = (w >= 0.f) ? lmx[nl][ol] : lmn[nl][ol];
    float v = leakyf((sel - mu)*rs*w + bb);
    feats[((long)b*256 + coff + og)*NP + n0 + nl] = v;
    if (WRITEH) lmx[nl][ol] = v;
    if (NEEDXX) xacc += v*v;
  }
  if (WRITEH){
    __syncthreads();
    #pragma unroll
    for(int k=0;k<8;k++){
      int flat = k*256 + t;
      int n = flat >> 5, cp = flat & 31;
      float v0 = lmx[n][2*cp], v1 = lmx[n][2*cp+1];
      unsigned short h0 = b16(v0), h1 = b16(v1);
      float r0 = v0 - __uint_as_float(((unsigned)h0)<<16);
      float r1 = v1 - __uint_as_float(((unsigned)h1)<<16);
      unsigned short l0 = b16(r0), l1 = b16(r1);
      long o = ((long)b*NP + n0 + n)*32 + cp;
      fhout[o] = (unsigned)h0 | ((unsigned)h1<<16);
      flout[o] = (unsigned)l0 | ((unsigned)l1<<16);
    }
  }
  if (NEEDXX){
    __syncthreads();
    float* red = &lmx[0][0];
    red[(t>>6)*64 + (t&63)] = xacc;
    __syncthreads();
    if (t < 64){
      float a = red[t] + red[64+t] + red[128+t] + red[192+t];
      xxout[b*NP + n0 + t] = a;
    }
  }
}

// ---------------- MFMA bf16 GEMM y=W@x (+bias/base, fused in-GN, out-stats, out-max/min) ----------------
template<bool WRITE_Y, bool DO_STATS, bool DO_MAXMIN, bool IN_NORM>
__global__ __launch_bounds__(256) void mgemm_kernel(
    const float* __restrict__ W, int ldw,
    const float* __restrict__ x, long xldb,
    const float* __restrict__ bias, const float* __restrict__ basev,
    int O, int C, int gshift,
    float* __restrict__ y, float* __restrict__ stats,
    unsigned* __restrict__ mmax, unsigned* __restrict__ mmin,
    const float* __restrict__ instats, const float* __restrict__ igw,
    const float* __restrict__ igb, int igshift, float iinv)
{
  __shared__ __align__(16) char WlB[128*80];
  __shared__ __align__(16) char XtB[128*80];
  __shared__ float sred[16];
  __shared__ unsigned smax[128];
  __shared__ unsigned smin[128];

  const int b  = blockIdx.z;
  const int o0 = blockIdx.y*128;
  const int nb = blockIdx.x*128;
  const int t  = threadIdx.x;
  const int lane = t & 63;
  const int wid = t >> 6;
  const int wmo = wid >> 1, wno = wid & 1;
  const int lr = lane & 15, lg = lane >> 4;

  if (DO_STATS && t < 16) sred[t] = 0.f;
  if (DO_MAXMIN && t < 128){ smax[t] = 0u; smin[t] = 0xFFFFFFFFu; }

  f32x4 acc[4][4];
  #pragma unroll
  for(int i=0;i<4;i++)
    #pragma unroll
    for(int j=0;j<4;j++) acc[i][j] = (f32x4){0.f,0.f,0.f,0.f};

  const int so  = t & 127;
  const int scb = (t >> 7) << 5;
  const int xcg = t >> 5;
  const int xng = t & 31;

  for(int cc=0; cc<C; cc+=32){
    __syncthreads();
    {
      const float* wp = W + (long)(o0 + so)*ldw + cc + (scb>>1);
      #pragma unroll
      for(int j=0;j<4;j++){
        float4 f = *(const float4*)(wp + j*4);
        uint2 v = { bf2(f.x,f.y), bf2(f.z,f.w) };
        *(uint2*)ldsW(WlB, so, scb + j*8) = v;
      }
    }
    {
      const float* xp = x + (long)b*xldb + (long)(cc + xcg*4)*NP + nb + xng*4;
      float4 f0 = *(const float4*)(xp);
      float4 f1 = *(const float4*)(xp + NP);
      float4 f2 = *(const float4*)(xp + 2*NP);
      float4 f3 = *(const float4*)(xp + 3*NP);
      float X4[4][4] = {{f0.x,f0.y,f0.z,f0.w},{f1.x,f1.y,f1.z,f1.w},
                        {f2.x,f2.y,f2.z,f2.w},{f3.x,f3.y,f3.z,f3.w}};
      if (IN_NORM){
        #pragma unroll
        for(int i=0;i<4;i++){
          int c = cc + xcg*4 + i;
          int g = c >> igshift;
          const float* sp = instats + ((long)b*(C>>igshift) + g)*2;
          float mu = sp[0]*iinv;
          float var = sp[1]*iinv - mu*mu;
          float rs = rsqrtf(var + EPSV);
          float aa = rs*igw[c];
          float c2 = igb[c] - mu*aa;
          #pragma unroll
          for(int j=0;j<4;j++) X4[i][j] = fmaxf(X4[i][j]*aa + c2, 0.f);
        }
      }
      #pragma unroll
      for(int j=0;j<4;j++){
        uint2 v = { bf2(X4[0][j], X4[1][j]), bf2(X4[2][j], X4[3][j]) };
        *(uint2*)ldsX(XtB, xng*4 + j, xcg*8) = v;
      }
    }
    __syncthreads();
    bf16x8 afr[4], bfr[4];
    #pragma unroll
    for(int mi=0;mi<4;mi++) afr[mi] = *(const bf16x8*)ldsW(WlB, wmo*64 + mi*16 + lr, lg*16);
    #pragma unroll
    for(int nj=0;nj<4;nj++) bfr[nj] = *(const bf16x8*)ldsX(XtB, wno*64 + nj*16 + lr, lg*16);
    #pragma unroll
    for(int mi=0;mi<4;mi++)
      #pragma unroll
      for(int nj=0;nj<4;nj++)
        acc[mi][nj] = __builtin_amdgcn_mfma_f32_16x16x32_bf16(afr[mi], bfr[nj], acc[mi][nj], 0, 0, 0);
  }

  float bb4[4][4];
  #pragma unroll
  for(int mi=0;mi<4;mi++){
    #pragma unroll
    for(int r=0;r<4;r++){
      int o = o0 + wmo*64 + mi*16 + lg*4 + r;
      float v = 0.f;
      if (bias)  v += bias[o];
      if (basev) v += basev[(long)b*O + o];
      bb4[mi][r] = v;
    }
  }
  #pragma unroll
  for(int mi=0;mi<4;mi++)
    #pragma unroll
    for(int nj=0;nj<4;nj++)
      #pragma unroll
      for(int r=0;r<4;r++) acc[mi][nj][r] += bb4[mi][r];

  if (WRITE_Y){
    #pragma unroll
    for(int mi=0;mi<4;mi++)
      #pragma unroll
      for(int nj=0;nj<4;nj++)
        #pragma unroll
        for(int r=0;r<4;r++){
          int o = o0 + wmo*64 + mi*16 + lg*4 + r;
          y[((long)b*O + o)*NP + nb + wno*64 + nj*16 + lr] = acc[mi][nj][r];
        }
  }
  if (DO_STATS){
    #pragma unroll
    for(int mi=0;mi<4;mi++){
      float s = 0.f, s2 = 0.f;
      #pragma unroll
      for(int nj=0;nj<4;nj++)
        #pragma unroll
        for(int r=0;r<4;r++){ float v = acc[mi][nj][r]; s += v; s2 += v*v; }
      int gi = (wmo*64 + mi*16) >> gshift;
      atomicAdd(&sred[gi*2],   s);
      atomicAdd(&sred[gi*2+1], s2);
    }
  }
  if (DO_MAXMIN){
    #pragma unroll
    for(int mi=0;mi<4;mi++)
      #pragma unroll
      for(int r=0;r<4;r++){
        float mv = acc[mi][0][r], mw = acc[mi][0][r];
        #pragma unroll
        for(int nj=1;nj<4;nj++){ mv = fmaxf(mv, acc[mi][nj][r]); mw = fminf(mw, acc[mi][nj][r]); }
        int ol = wmo*64 + mi*16 + lg*4 + r;
        atomicMax(&smax[ol], fenc(mv));
        atomicMin(&smin[ol], fenc(mw));
      }
  }
  if (DO_STATS || DO_MAXMIN) __syncthreads();
  if (DO_STATS){
    int ngb = 128 >> gshift;
    if (t < ngb*2){
      atomicAdd(&stats[((long)b*(O>>gshift) + (o0>>gshift) + (t>>1))*2 + (t&1)], sred[t]);
    }
  }
  if (DO_MAXMIN){
    if (t < 128){
      atomicMax(&mmax[(long)b*O + o0 + t], smax[t]);
      atomicMin(&mmin[(long)b*O + o0 + t], smin[t]);
    }
  }
}

// ---------------- xmax = relu(gn(max/min over n)) ----------------
__global__ void xmax_kernel(const unsigned* __restrict__ mmax, const unsigned* __restrict__ mmin,
                            const float* __restrict__ stats, const float* __restrict__ gw,
                            const float* __restrict__ gb, float* __restrict__ xmax){
  int t = blockIdx.x*256 + threadIdx.x;
  int b = t >> 10, o = t & 1023;
  int g = o >> 5;
  const float* sp = stats + (b*32+g)*2;
  const float inv_cnt = 1.f/(32.f*NP);
  float mu = sp[0]*inv_cnt;
  float var = sp[1]*inv_cnt - mu*mu;
  float rs = rsqrtf(var + EPSV);
  float w = gw[o];
  float sel = (w >= 0.f) ? fdec(mmax[t]) : fdec(mmin[t]);
  float v = (sel - mu)*rs*w + gb[o];
  xmax[t] = fmaxf(v, 0.f);
}

// ---------------- base1[b,o] = bs1[o] + Ws1[:, :1024] @ xmax[b] ----------------
__global__ __launch_bounds__(256) void base1_kernel(const float* __restrict__ Ws1, const float* __restrict__ bs1,
                                                    const float* __restrict__ xmax, float* __restrict__ base1){
  __shared__ float sred[4][8];
  const int o = blockIdx.x;
  const int t = threadIdx.x;
  const float* wp = Ws1 + (long)o*1280;
  float acc[8];
  #pragma unroll
  for(int bb=0;bb<8;bb++) acc[bb]=0.f;
  #pragma unroll
  for(int cc=0;cc<4;cc++){
    int c = cc*256 + t;
    float w = wp[c];
    #pragma unroll
    for(int bb=0;bb<8;bb++) acc[bb] += w * xmax[bb*1024 + c];
  }
  #pragma unroll
  for(int bb=0;bb<8;bb++){
    float a = acc[bb];
    a += __shfl_xor(a,1);  a += __shfl_xor(a,2);  a += __shfl_xor(a,4);
    a += __shfl_xor(a,8);  a += __shfl_xor(a,16); a += __shfl_xor(a,32);
    acc[bb]=a;
  }
  if ((t&63)==0){
    #pragma unroll
    for(int bb=0;bb<8;bb++) sred[t>>6][bb]=acc[bb];
  }
  __syncthreads();
  if (t<8){
    float a = sred[0][t]+sred[1][t]+sred[2][t]+sred[3][t] + bs1[o];
    base1[t*512 + o] = a;
  }
}

// ---------------- final: fused GN3+relu + 50-class conv + log_softmax ----------------
__global__ __launch_bounds__(256) void s4_kernel(const float* __restrict__ h3raw,
                                                 const float* __restrict__ stats,
                                                 const float* __restrict__ gw, const float* __restrict__ gb,
                                                 const float* __restrict__ W,
                                                 const float* __restrict__ bias,
                                                 float* __restrict__ out){
  const int b = blockIdx.y;
  const int n = blockIdx.x*64 + (threadIdx.x>>2);
  const int cl = threadIdx.x & 3;
  const float inv_cnt = 1.f/(16.f*NP);
  float mu0, rs0, mu1, rs1;
  {
    const float* sp = stats + (b*8 + cl*2)*2;
    mu0 = sp[0]*inv_cnt;
    float var = sp[1]*inv_cnt - mu0*mu0;
    rs0 = rsqrtf(var + EPSV);
    const float* sp1 = stats + (b*8 + cl*2 + 1)*2;
    mu1 = sp1[0]*inv_cnt;
    float var1 = sp1[1]*inv_cnt - mu1*mu1;
    rs1 = rsqrtf(var1 + EPSV);
  }
  float hv[32];
  #pragma unroll
  for(int c=0;c<32;c++){
    int og = cl*32 + c;
    float rs = (c < 16) ? rs0 : rs1;
    float mu = (c < 16) ? mu0 : mu1;
    float a = rs*gw[og];
    float c2 = gb[og] - mu*a;
    float v = h3raw[((long)b*128 + og)*NP + n];
    hv[c] = fmaxf(v*a + c2, 0.f);
  }
  float zz[50];
  #pragma unroll
  for(int o=0;o<50;o++){
    const float* wp = W + o*128 + cl*32;
    float a = 0.f;
    #pragma unroll
    for(int c=0;c<32;c++) a += wp[c]*hv[c];
    a += __shfl_xor(a,1);
    a += __shfl_xor(a,2);
    zz[o] = a + bias[o];
  }
  float m = zz[0];
  #pragma unroll
  for(int o=1;o<50;o++) m = fmaxf(m, zz[o]);
  float s = 0.f;
  #pragma unroll
  for(int o=0;o<50;o++) s += __expf(zz[o]-m);
  float lse = m + __logf(s);
  #pragma unroll
  for(int o=0;o<50;o++){
    if ((o&3)==cl) out[((long)b*50+o)*NP+n] = zz[o]-lse;
  }
}

extern "C" void kernel_launch(void* const* d_in, const int* in_sizes, int n_in,
                              void* d_out, int out_size, void* d_ws, size_t ws_size,
                              hipStream_t stream)
{
  const float* x   = (const float*)d_in[0];
  const float* W1  = (const float*)d_in[1];
  const float* W2  = (const float*)d_in[2];
  const float* W3  = (const float*)d_in[3];
  const float* g1w = (const float*)d_in[4];
  const float* g1b = (const float*)d_in[5];
  const float* g2w = (const float*)d_in[6];
  const float* g2b = (const float*)d_in[7];
  const float* g3w = (const float*)d_in[8];
  const float* g3b = (const float*)d_in[9];
  const float* gfw = (const float*)d_in[10];
  const float* gfb = (const float*)d_in[11];
  const float* gs1w= (const float*)d_in[12];
  const float* gs1b= (const float*)d_in[13];
  const float* gs2w= (const float*)d_in[14];
  const float* gs2b= (const float*)d_in[15];
  const float* gs3w= (const float*)d_in[16];
  const float* gs3b= (const float*)d_in[17];
  const float* Wm  = (const float*)d_in[18];
  const float* bm  = (const float*)d_in[19];
  const float* Ws1 = (const float*)d_in[20];
  const float* bs1 = (const float*)d_in[21];
  const float* Ws2 = (const float*)d_in[22];
  const float* bs2 = (const float*)d_in[23];
  const float* Ws3 = (const float*)d_in[24];
  const float* bs3 = (const float*)d_in[25];
  const float* Ws4 = (const float*)d_in[26];
  const float* bs4 = (const float*)d_in[27];
  float* out = (float*)d_out;

  char* ws = (char*)d_ws;
  size_t off = 0;
  auto alloc = [&](size_t bytes)->char*{
    char* p = ws + off;
    off += (bytes + 255) & ~(size_t)255;
    return p;
  };
  char* zbase = alloc(6656 + 32768);
  float* estats1 = (float*)(zbase + 0);
  float* estats2 = (float*)(zbase + 512);
  float* estats3 = (float*)(zbase + 1024);
  float* mstats  = (float*)(zbase + 1536);
  float* s1stats = (float*)(zbase + 3584);
  float* s2stats = (float*)(zbase + 4608);
  float* s3stats = (float*)(zbase + 5632);
  unsigned* mmax = (unsigned*)(zbase + 6656);
  unsigned* mmin = (unsigned*)alloc(32768);
  float* xmaxb = (float*)alloc(8*1024*4);
  float* base1 = (float*)alloc(8*512*4);
  float* feats = (float*)alloc((size_t)BN*256*NP*4);
  int*   idxb  = (int*)  alloc((size_t)BN*NP*KK*4);
  float* xxb   = (float*)alloc((size_t)BN*NP*4);
  unsigned* fhb = (unsigned*)alloc((size_t)BN*NP*64*2);
  unsigned* flb = (unsigned*)alloc((size_t)BN*NP*64*2);
  float* ya    = (float*)alloc((size_t)BN*NP*128*4);
  float* dd    = (float*)alloc((size_t)BN*NP*128*4);
  float* mx    = (float*)alloc((size_t)BN*NP*128*4);
  float* mn    = (float*)alloc((size_t)BN*NP*128*4);
  float* ybuf1 = (float*)alloc((size_t)BN*512*NP*4);
  float* ybuf2 = (float*)alloc((size_t)BN*256*NP*4);
  float* ybuf3 = (float*)alloc((size_t)BN*128*NP*4);

  // pk (41.9MB) aliases ya..mn — consumers strictly ordered after merge.
  unsigned* pk = (unsigned*)ya;
  const unsigned short* fh16 = (const unsigned short*)fhb;
  const unsigned short* fl16 = (const unsigned short*)flb;

  hipMemsetAsync(zbase, 0, 6656 + 32768, stream);
  hipMemsetAsync(mmin, 0xFF, 32768, stream);

  dim3 blk256(256);

  // ---- edge block 1 (C=3 -> 64) ----
  xx_kernel<<<dim3(NP/256, BN), blk256, 0, stream>>>(x, (long)3*NP, 3, xxb);
  knn1_kernel<<<dim3(NP/64, 8, BN), blk256, 0, stream>>>(x, xxb, pk);
  knnmerge_kernel<<<dim3(BN*NP/4), blk256, 0, stream>>>(pk, idxb);
  pcdual_kernel<3,64><<<dim3(NP/4, BN), blk256, 0, stream>>>(x, (long)3*NP, W1, ya, dd);
  egather_kernel<64><<<dim3(8*NP/32), blk256, 0, stream>>>(ya, dd, idxb, mx, mn, estats1);
  enorm_kernel<64,true,true><<<dim3(NP/64, 1, BN), blk256, 0, stream>>>(
      mx, mn, estats1, g1w, g1b, feats, 0, xxb, fhb, flb);

  // ---- edge block 2 (C=64 -> 64) ----
  knnf_kernel<<<dim3(NP/64, 8, BN), blk256, 0, stream>>>(fh16, fl16, xxb, pk);
  knnmerge_kernel<<<dim3(BN*NP/4), blk256, 0, stream>>>(pk, idxb);
  pcdualm_kernel<64><<<dim3(NP/64, BN), blk256, 0, stream>>>(fh16, fl16, W2, ya, dd);
  egather_kernel<64><<<dim3(8*NP/32), blk256, 0, stream>>>(ya, dd, idxb, mx, mn, estats2);
  enorm_kernel<64,true,true><<<dim3(NP/64, 1, BN), blk256, 0, stream>>>(
      mx, mn, estats2, g2w, g2b, feats, 64, xxb, fhb, flb);

  // ---- edge block 3 (C=64 -> 128) ----
  knnf_kernel<<<dim3(NP/64, 8, BN), blk256, 0, stream>>>(fh16, fl16, xxb, pk);
  knnmerge_kernel<<<dim3(BN*NP/4), blk256, 0, stream>>>(pk, idxb);
  pcdualm_kernel<128><<<dim3(NP/64, BN), blk256, 0, stream>>>(fh16, fl16, W3, ya, dd);
  egather_kernel<128><<<dim3(8*NP/32), blk256, 0, stream>>>(ya, dd, idxb, mx, mn, estats3);
  enorm_kernel<128,false,false><<<dim3(NP/64, 2, BN), blk256, 0, stream>>>(
      mx, mn, estats3, g3w, g3b, feats, 128, nullptr, nullptr, nullptr);

  // ---- global conv (Wm 1024x256): stats + per-(b,o) max/min only ----
  mgemm_kernel<false,true,true,false><<<dim3(16,8,BN), blk256, 0, stream>>>(
      Wm, 256, feats, (long)256*NP, bm, nullptr, 1024, 256, 5,
      nullptr, mstats, mmax, mmin, nullptr, nullptr, nullptr, 0, 0.f);
  xmax_kernel<<<dim3(32), blk256, 0, stream>>>(mmax, mmin, mstats, gfw, gfb, xmaxb);
  base1_kernel<<<dim3(512), blk256, 0, stream>>>(Ws1, bs1, xmaxb, base1);

  // ---- seg conv 1 ----
  mgemm_kernel<true,true,false,false><<<dim3(16,4,BN), blk256, 0, stream>>>(
      Ws1 + 1024, 1280, feats, (long)256*NP, nullptr, base1, 512, 256, 5,
      ybuf1, s1stats, nullptr, nullptr, nullptr, nullptr, nullptr, 0, 0.f);

  // ---- seg conv 2 (fused GN1+relu on input) ----
  mgemm_kernel<true,true,false,true><<<dim3(16,2,BN), blk256, 0, stream>>>(
      Ws2, 512, ybuf1, (long)512*NP, bs2, nullptr, 256, 512, 4,
      ybuf2, s2stats, nullptr, nullptr, s1stats, gs1w, gs1b, 5, 1.f/(32.f*NP));

  // ---- seg conv 3 (fused GN2+relu on input) ----
  mgemm_kernel<true,true,false,true><<<dim3(16,1,BN), blk256, 0, stream>>>(
      Ws3, 256, ybuf2, (long)256*NP, bs3, nullptr, 128, 256, 4,
      ybuf3, s3stats, nullptr, nullptr, s2stats, gs2w, gs2b, 4, 1.f/(16.f*NP));

  // ---- final: fused GN3+relu + conv + log_softmax ----
  s4_kernel<<<dim3(NP/64, BN), blk256, 0, stream>>>(ybuf3, s3stats, gs3w, gs3b, Ws4, bs4, out);
}

// Round 20
// 533.110 us; speedup vs baseline: 1.0708x; 1.0058x over previous
//
#include <hip/hip_runtime.h>

#define BN 8
#define NP 2048
#define KK 20
#define EPSV 1e-5f

typedef __attribute__((ext_vector_type(8))) short bf16x8;
typedef __attribute__((ext_vector_type(4))) float f32x4;

static __device__ __forceinline__ float leakyf(float v){ return v >= 0.f ? v : 0.2f*v; }
static __device__ __forceinline__ unsigned fenc(float f){
  unsigned u = __float_as_uint(f);
  unsigned m = (unsigned)((int)u >> 31);
  return u ^ (m | 0x80000000u);
}
static __device__ __forceinline__ float fdec(unsigned u){
  return __uint_as_float((u & 0x80000000u) ? (u & 0x7FFFFFFFu) : ~u);
}
static __device__ __forceinline__ unsigned bf2(float a, float b){
  unsigned ua = __float_as_uint(a), ub = __float_as_uint(b);
  ua = (ua + 0x7FFFu + ((ua>>16)&1u)) >> 16;
  ub = (ub + 0x7FFFu + ((ub>>16)&1u)) >> 16;
  return ua | (ub<<16);
}
static __device__ __forceinline__ unsigned short b16(float v){
  unsigned u = __float_as_uint(v);
  return (unsigned short)((u + 0x7FFFu + ((u>>16)&1u)) >> 16);
}
static __device__ __forceinline__ unsigned umax32(unsigned a, unsigned b){ return __builtin_elementwise_max(a,b); }
static __device__ __forceinline__ unsigned med3u(unsigned a, unsigned b, unsigned c){
  unsigned d;
  asm("v_med3_u32 %0, %1, %2, %3" : "=v"(d) : "v"(a), "v"(b), "v"(c));
  return d;
}

// LDS addressing for mgemm: 80B rows, XOR swizzle on bits 4-5.
static __device__ __forceinline__ char* ldsW(char* base, int row, int colb){
  return base + row*80 + (colb ^ ((((unsigned)row>>3)&3u)<<4));
}
static __device__ __forceinline__ char* ldsX(char* base, int row, int colb){
  return base + row*80 + (colb ^ (((((unsigned)row>>2)^((unsigned)row>>4))&3u)<<4));
}
static __device__ __forceinline__ int swz128(int row, int colb){
  return (colb ^ ((row&7)<<4));
}

// ---------------- xx = sum_c x^2 (block1 only, on raw x) ----------------
__global__ __launch_bounds__(256) void xx_kernel(const float* __restrict__ x, long ldb, int C,
                                                 float* __restrict__ xx){
  int b = blockIdx.y;
  int n = blockIdx.x*256 + threadIdx.x;
  const float* xp = x + (long)b*ldb + n;
  float a = 0.f;
  for(int c=0;c<C;c++){ float v = xp[(long)c*NP]; a += v*v; }
  xx[b*NP + n] = a;
}

// ---------------- branch-free u32 key insert: 1 med3 per position ----------------
static __device__ __forceinline__ void ins20(unsigned* tv, unsigned key){
  unsigned pold = tv[0];
  tv[0] = umax32(tv[0], key);
  #pragma unroll
  for(int r=1;r<20;r++){
    unsigned cold = tv[r];
    tv[r] = med3u(key, pold, cold);
    pold = cold;
  }
}

// ---------------- knn C=64 v4: candidates cooperatively staged in LDS ----------------
__global__ __launch_bounds__(256) void knnf_kernel(const unsigned short* __restrict__ fh,
                                                   const unsigned short* __restrict__ fl,
                                                   const float* __restrict__ xx,
                                                   unsigned* __restrict__ pk){
  __shared__ unsigned short CH[64][68];
  __shared__ unsigned short CL[64][68];
  __shared__ unsigned SK[64][68];
  __shared__ float cxs[64];
  const int b    = blockIdx.z;
  const int part = blockIdx.y;
  const int q0   = blockIdx.x*64;
  const int t    = threadIdx.x;
  const int lane = t & 63;
  const int w    = t >> 6;
  const int lr   = lane & 15, lg = lane >> 4;
  const unsigned short* fhb = fh + (long)b*NP*64;
  const unsigned short* flb = fl + (long)b*NP*64;
  const float* xxb = xx + b*NP;

  const unsigned short* qa = fhb + ((long)(q0 + w*16 + lr))*64 + lg*8;
  const unsigned short* qb = flb + ((long)(q0 + w*16 + lr))*64 + lg*8;
  bf16x8 ah0 = *(const bf16x8*)(qa);
  bf16x8 ah1 = *(const bf16x8*)(qa + 32);
  bf16x8 al0 = *(const bf16x8*)(qb);
  bf16x8 al1 = *(const bf16x8*)(qb + 32);
  float4 qxx4 = *(const float4*)(xxb + q0 + w*16 + lg*4);
  float qxx[4] = {qxx4.x, qxx4.y, qxx4.z, qxx4.w};

  unsigned tv[20];
  #pragma unroll
  for(int r=0;r<20;r++) tv[r] = 0u;
  const int sq = t>>2, sl = t&3;

  #define STAGE(ct_)                                                                  \
    {                                                                                 \
      const int ct__ = (ct_);                                                         \
      _Pragma("unroll")                                                               \
      for(int i = t; i < 512; i += 256){                                              \
        int row = i >> 3, seg = i & 7;                                                \
        *(uint4*)&CH[row][seg*8] = *(const uint4*)(fhb + ((long)(ct__*64+row))*64 + seg*8); \
        *(uint4*)&CL[row][seg*8] = *(const uint4*)(flb + ((long)(ct__*64+row))*64 + seg*8); \
      }                                                                               \
      if (t < 64) cxs[t] = xxb[ct__*64 + t];                                          \
    }

  STAGE(part*4);
  __syncthreads();

  #pragma unroll
  for(int cc=0; cc<4; cc++){
    __builtin_amdgcn_s_setprio(1);
    f32x4 acc[4];
    #pragma unroll
    for(int nt=0; nt<4; nt++){
      int crow = nt*16 + lr;
      bf16x8 bh0 = *(const bf16x8*)&CH[crow][lg*8];
      bf16x8 bh1 = *(const bf16x8*)&CH[crow][32 + lg*8];
      bf16x8 bl0 = *(const bf16x8*)&CL[crow][lg*8];
      bf16x8 bl1 = *(const bf16x8*)&CL[crow][32 + lg*8];
      f32x4 a = (f32x4){0.f,0.f,0.f,0.f};
      a = __builtin_amdgcn_mfma_f32_16x16x32_bf16(ah0, bh0, a, 0,0,0);
      a = __builtin_amdgcn_mfma_f32_16x16x32_bf16(ah1, bh1, a, 0,0,0);
      a = __builtin_amdgcn_mfma_f32_16x16x32_bf16(ah0, bl0, a, 0,0,0);
      a = __builtin_amdgcn_mfma_f32_16x16x32_bf16(ah1, bl1, a, 0,0,0);
      a = __builtin_amdgcn_mfma_f32_16x16x32_bf16(al0, bh0, a, 0,0,0);
      a = __builtin_amdgcn_mfma_f32_16x16x32_bf16(al1, bh1, a, 0,0,0);
      acc[nt] = a;
    }
    __builtin_amdgcn_s_setprio(0);
    float cxv[4];
    #pragma unroll
    for(int nt=0; nt<4; nt++) cxv[nt] = cxs[nt*16 + lr];
    unsigned key4[4][4];
    #pragma unroll
    for(int nt=0; nt<4; nt++){
      #pragma unroll
      for(int r=0;r<4;r++){
        float neg = 2.f*acc[nt][r] - qxx[r] - cxv[nt];
        key4[nt][r] = (fenc(neg) & 0xFFFFFF00u) | (255u - (unsigned)(cc*64 + nt*16 + lr));
      }
    }
    __syncthreads();
    #pragma unroll
    for(int nt=0; nt<4; nt++)
      #pragma unroll
      for(int r=0;r<4;r++)
        SK[w*16 + lg*4 + r][nt*16 + lr] = key4[nt][r];
    if (cc < 3){
      STAGE(part*4 + cc + 1);
    }
    __syncthreads();
    #pragma unroll
    for(int jj=0;jj<4;jj++){
      uint4 kv = *(const uint4*)&SK[sq][sl*16 + jj*4];
      ins20(tv, kv.x); ins20(tv, kv.y); ins20(tv, kv.z); ins20(tv, kv.w);
    }
  }
  #undef STAGE
  long base = ((((long)b*NP + q0 + sq)*8 + part)*4 + sl)*20;
  #pragma unroll
  for(int r=0;r<20;r++) pk[base+r] = tv[r];
}

// ---------------- knn C=3 direct ----------------
__global__ __launch_bounds__(256) void knn1_kernel(const float* __restrict__ x,
                                                   const float* __restrict__ xx,
                                                   unsigned* __restrict__ pk){
  __shared__ float cx0[256], cx1[256], cx2[256], cxxa[256];
  const int b    = blockIdx.z;
  const int part = blockIdx.y;
  const int q0   = blockIdx.x*64;
  const int t    = threadIdx.x;
  const float* xb  = x + (long)b*3*NP;
  const float* xxb = xx + b*NP;

  cx0[t]  = xb[part*256 + t];
  cx1[t]  = xb[NP + part*256 + t];
  cx2[t]  = xb[2*NP + part*256 + t];
  cxxa[t] = xxb[part*256 + t];

  const int sq = t>>2, sl = t&3;
  const int q = q0 + sq;
  float qx = xb[q], qy = xb[NP + q], qz = xb[2*NP + q];
  float qxx = xxb[q];
  __syncthreads();

  unsigned tv[20];
  #pragma unroll
  for(int r=0;r<20;r++) tv[r] = 0u;

  for(int cc=0; cc<4; cc++){
    #pragma unroll
    for(int j=0;j<16;j++){
      int m = cc*64 + sl*16 + j;
      float ip = qx*cx0[m] + qy*cx1[m] + qz*cx2[m];
      float neg = 2.f*ip - qxx - cxxa[m];
      unsigned key = (fenc(neg) & 0xFFFFFF00u) | (255u - (unsigned)m);
      ins20(tv, key);
    }
  }
  long base = ((((long)b*NP + q0 + sq)*8 + part)*4 + sl)*20;
  #pragma unroll
  for(int r=0;r<20;r++) pk[base+r] = tv[r];
}

// ---------------- wave-parallel merge ----------------
__global__ __launch_bounds__(256) void knnmerge_kernel(const unsigned* __restrict__ pk,
                                                       int* __restrict__ idxout){
  const int wid  = threadIdx.x >> 6;
  const int lane = threadIdx.x & 63;
  const long qg = (long)blockIdx.x*4 + wid;
  const unsigned* kb = pk + qg*640;
  const int l = lane >> 1, h = lane & 1;
  unsigned k[10];
  {
    const unsigned* src = kb + l*20 + h*10;
    #pragma unroll
    for(int i=0;i<10;i++) k[i] = src[i];
  }
  int rem = 10;
  int* op = idxout + qg*KK;
  const int gbase = (l>>2)*256;
  for(int r=0;r<KK;r++){
    unsigned key = k[0];
    int gi = gbase + 255 - (int)(key & 255u);
    unsigned long long cmp = (rem > 0)
        ? ((unsigned long long)(key & 0xFFFFFF00u) << 32) | (unsigned)(0x7FFFFFFF - gi)
        : 0ull;
    unsigned long long w = cmp;
    #pragma unroll
    for(int s=1;s<64;s<<=1){
      unsigned long long o = __shfl_xor(w, s, 64);
      w = (o > w) ? o : w;
    }
    if (lane == 0){
      op[r] = 0x7FFFFFFF - (int)(unsigned)(w & 0xFFFFFFFFu);
    }
    if (cmp == w){
      #pragma unroll
      for(int i=0;i<9;i++) k[i] = k[i+1];
      rem--;
    }
  }
}

// ---------------- edge conv C=3: vector ----------------
template<int CIN, int O>
__global__ __launch_bounds__(256) void pcdual_kernel(const float* __restrict__ x, long ldb,
                                                     const float* __restrict__ W,
                                                     float* __restrict__ ya, float* __restrict__ dd){
  __shared__ float Wt[CIN][O+1];
  constexpr int NLOC = 256/O;
  const int b = blockIdx.y;
  const int n0 = blockIdx.x*NLOC;
  const int t = threadIdx.x;
  const int o = t % O;
  const int n = n0 + t/O;
  const float* xp = x + (long)b*ldb + n;
  float xv[CIN];
  #pragma unroll
  for(int c=0;c<CIN;c++) xv[c] = xp[(long)c*NP];
  for(int i=t;i<CIN*O;i+=256){ int oo=i/CIN, c=i%CIN; Wt[c][oo] = W[(long)oo*2*CIN + c]; }
  __syncthreads();
  float aa = 0.f;
  #pragma unroll
  for(int c=0;c<CIN;c++) aa += Wt[c][o]*xv[c];
  __syncthreads();
  for(int i=t;i<CIN*O;i+=256){ int oo=i/CIN, c=i%CIN; Wt[c][oo] = W[(long)oo*2*CIN + CIN + c]; }
  __syncthreads();
  float ab = 0.f;
  #pragma unroll
  for(int c=0;c<CIN;c++) ab += Wt[c][o]*xv[c];
  long outoff = ((long)b*NP + n)*O + o;
  ya[outoff] = aa;
  dd[outoff] = ab - aa;
}

// ---------------- edge conv C=64 via MFMA from bf16 hi/lo mirrors; OSPL-way o-split ----------------
template<int O, int OSPL>
__global__ __launch_bounds__(256) void pcdualm_kernel(const unsigned short* __restrict__ fh,
                                                      const unsigned short* __restrict__ fl,
                                                      const float* __restrict__ W,
                                                      float* __restrict__ ya, float* __restrict__ dd){
  constexpr int OH = O/OSPL;
  __shared__ unsigned short AH[OH][64];
  __shared__ unsigned short AL[OH][64];
  __shared__ unsigned short DH[OH][64];
  __shared__ unsigned short DL[OH][64];
  const int b  = blockIdx.z;
  const int ob = blockIdx.y * OH;          // o-base of this split
  const int n0 = blockIdx.x*64;
  const int t  = threadIdx.x;
  const int lane = t & 63;
  const int w  = t >> 6;
  const int lr = lane & 15, lg = lane >> 4;

  for(int i=t; i<OH*64; i+=256){
    int o = i >> 6, c = i & 63;
    float va = W[(long)(ob+o)*128 + c];
    float vb = W[(long)(ob+o)*128 + 64 + c];
    float vd = vb - va;
    unsigned short ah = b16(va);
    unsigned short dh = b16(vd);
    int byt = swz128(o, c*2);
    *(unsigned short*)((char*)&AH[o][0] + byt) = ah;
    *(unsigned short*)((char*)&AL[o][0] + byt) = b16(va - __uint_as_float(((unsigned)ah)<<16));
    *(unsigned short*)((char*)&DH[o][0] + byt) = dh;
    *(unsigned short*)((char*)&DL[o][0] + byt) = b16(vd - __uint_as_float(((unsigned)dh)<<16));
  }

  const int n = n0 + w*16 + lr;
  const unsigned short* xh = fh + ((long)b*NP + n)*64 + lg*8;
  const unsigned short* xl = fl + ((long)b*NP + n)*64 + lg*8;
  bf16x8 xh0 = *(const bf16x8*)(xh);
  bf16x8 xh1 = *(const bf16x8*)(xh + 32);
  bf16x8 xl0 = *(const bf16x8*)(xl);
  bf16x8 xl1 = *(const bf16x8*)(xl + 32);
  __syncthreads();

  #pragma unroll
  for(int mi=0; mi<OH/16; mi++){
    int row = mi*16 + lr;
    bf16x8 a_h0 = *(const bf16x8*)((char*)&AH[row][0] + swz128(row, lg*16));
    bf16x8 a_h1 = *(const bf16x8*)((char*)&AH[row][0] + swz128(row, 64 + lg*16));
    bf16x8 a_l0 = *(const bf16x8*)((char*)&AL[row][0] + swz128(row, lg*16));
    bf16x8 a_l1 = *(const bf16x8*)((char*)&AL[row][0] + swz128(row, 64 + lg*16));
    f32x4 aa = (f32x4){0.f,0.f,0.f,0.f};
    aa = __builtin_amdgcn_mfma_f32_16x16x32_bf16(a_h0, xh0, aa, 0,0,0);
    aa = __builtin_amdgcn_mfma_f32_16x16x32_bf16(a_h1, xh1, aa, 0,0,0);
    aa = __builtin_amdgcn_mfma_f32_16x16x32_bf16(a_h0, xl0, aa, 0,0,0);
    aa = __builtin_amdgcn_mfma_f32_16x16x32_bf16(a_h1, xl1, aa, 0,0,0);
    aa = __builtin_amdgcn_mfma_f32_16x16x32_bf16(a_l0, xh0, aa, 0,0,0);
    aa = __builtin_amdgcn_mfma_f32_16x16x32_bf16(a_l1, xh1, aa, 0,0,0);
    bf16x8 d_h0 = *(const bf16x8*)((char*)&DH[row][0] + swz128(row, lg*16));
    bf16x8 d_h1 = *(const bf16x8*)((char*)&DH[row][0] + swz128(row, 64 + lg*16));
    bf16x8 d_l0 = *(const bf16x8*)((char*)&DL[row][0] + swz128(row, lg*16));
    bf16x8 d_l1 = *(const bf16x8*)((char*)&DL[row][0] + swz128(row, 64 + lg*16));
    f32x4 ad = (f32x4){0.f,0.f,0.f,0.f};
    ad = __builtin_amdgcn_mfma_f32_16x16x32_bf16(d_h0, xh0, ad, 0,0,0);
    ad = __builtin_amdgcn_mfma_f32_16x16x32_bf16(d_h1, xh1, ad, 0,0,0);
    ad = __builtin_amdgcn_mfma_f32_16x16x32_bf16(d_h0, xl0, ad, 0,0,0);
    ad = __builtin_amdgcn_mfma_f32_16x16x32_bf16(d_h1, xl1, ad, 0,0,0);
    ad = __builtin_amdgcn_mfma_f32_16x16x32_bf16(d_l0, xh0, ad, 0,0,0);
    ad = __builtin_amdgcn_mfma_f32_16x16x32_bf16(d_l1, xh1, ad, 0,0,0);
    long ooff = ((long)b*NP + n)*O + ob + mi*16 + lg*4;
    float4 va = {aa[0],aa[1],aa[2],aa[3]};
    float4 vd = {ad[0],ad[1],ad[2],ad[3]};
    *(float4*)(ya + ooff) = va;
    *(float4*)(dd + ooff) = vd;
  }
}

// ---------------- edge gather v3 ----------------
template<int O>
__global__ __launch_bounds__(256) void egather_kernel(const float* __restrict__ ya, const float* __restrict__ dd,
                               const int* __restrict__ idx,
                               float* __restrict__ mx, float* __restrict__ mn,
                               float* __restrict__ stats){
  __shared__ float sred2[4][16];
  constexpr int NSUB = 256/O;
  constexpr int CPG = O/8;
  const int b  = blockIdx.x & 7;
  const int n0 = (blockIdx.x >> 3) * 32;
  const int t = threadIdx.x;
  const int w = t >> 6;
  const int o = t % O;
  const int ns = t / O;
  if (t < 64) sred2[t>>4][t&15] = 0.f;
  __syncthreads();
  float gs = 0.f, gs2 = 0.f;
  const float* yab = ya + (long)b*NP*O;
  for(int p=ns; p<32; p+=NSUB){
    int n = n0 + p;
    float d = dd[((long)b*NP + n)*O + o];
    const int* ip = idx + ((long)b*NP + n)*KK;
    float m = -__builtin_inff(), mm = __builtin_inff(), s = 0.f, s2 = 0.f;
    #pragma unroll
    for(int k=0;k<KK;k++){
      int j = ip[k];
      float v = yab[(long)j*O + o] + d;
      s += v; s2 += v*v;
      m = fmaxf(m, v); mm = fminf(mm, v);
    }
    mx[((long)b*NP + n)*O + o] = m;
    mn[((long)b*NP + n)*O + o] = mm;
    gs += s; gs2 += s2;
  }
  #pragma unroll
  for(int offm=1; offm<CPG; offm<<=1){
    gs  += __shfl_xor(gs,  offm, CPG);
    gs2 += __shfl_xor(gs2, offm, CPG);
  }
  if ((o & (CPG-1)) == 0){
    int g = o / CPG;
    sred2[w][g*2]   = gs;
    sred2[w][g*2+1] = gs2;
  }
  __syncthreads();
  if (t < 16){
    float a = sred2[0][t] + sred2[1][t] + sred2[2][t] + sred2[3][t];
    atomicAdd(&stats[b*16 + t], a);
  }
}

// ---------------- edge normalize (+leaky), transpose into feats; optional bf16 hi/lo + xx ----------------
template<int O, bool NEEDXX, bool WRITEH>
__global__ __launch_bounds__(256) void enorm_kernel(const float* __restrict__ mx, const float* __restrict__ mn,
                                                    const float* __restrict__ stats,
                                                    const float* __restrict__ gw, const float* __restrict__ gb,
                                                    float* __restrict__ feats, int coff,
                                                    float* __restrict__ xxout,
                                                    unsigned* __restrict__ fhout, unsigned* __restrict__ flout){
  __shared__ float lmx[64][65];
  __shared__ float lmn[64][65];
  const int b = blockIdx.z;
  const int o0 = blockIdx.y*64;
  const int n0 = blockIdx.x*64;
  const int t = threadIdx.x;
  for(int r=0;r<16;r++){
    int i = r*4 + t/64, j = t%64;
    long src = ((long)b*NP + n0 + i)*O + o0 + j;
    lmx[i][j] = mx[src];
    lmn[i][j] = mn[src];
  }
  __syncthreads();
  constexpr int CPG = O/8;
  const float inv_cnt = 1.f/((float)CPG*NP*KK);
  float xacc = 0.f;
  for(int r=0;r<16;r++){
    int ol = r*4 + t/64, nl = t%64;
    int og = o0 + ol;
    int g = og / CPG;
    float S  = stats[(b*8+g)*2];
    float S2 = stats[(b*8+g)*2+1];
    float mu = S*inv_cnt;
    float var = S2*inv_cnt - mu*mu;
    float rs = rsqrtf(var + EPSV);
    float w = gw[og], bb = gb[og];
    float sel = (w >= 0.f) ? lmx[nl][ol] : lmn[nl][ol];
    float v = leakyf((sel - mu)*rs*w + bb);
    feats[((long)b*256 + coff + og)*NP + n0 + nl] = v;
    if (WRITEH) lmx[nl][ol] = v;
    if (NEEDXX) xacc += v*v;
  }
  if (WRITEH){
    __syncthreads();
    #pragma unroll
    for(int k=0;k<8;k++){
      int flat = k*256 + t;
      int n = flat >> 5, cp = flat & 31;
      float v0 = lmx[n][2*cp], v1 = lmx[n][2*cp+1];
      unsigned short h0 = b16(v0), h1 = b16(v1);
      float r0 = v0 - __uint_as_float(((unsigned)h0)<<16);
      float r1 = v1 - __uint_as_float(((unsigned)h1)<<16);
      unsigned short l0 = b16(r0), l1 = b16(r1);
      long o = ((long)b*NP + n0 + n)*32 + cp;
      fhout[o] = (unsigned)h0 | ((unsigned)h1<<16);
      flout[o] = (unsigned)l0 | ((unsigned)l1<<16);
    }
  }
  if (NEEDXX){
    __syncthreads();
    float* red = &lmx[0][0];
    red[(t>>6)*64 + (t&63)] = xacc;
    __syncthreads();
    if (t < 64){
      float a = red[t] + red[64+t] + red[128+t] + red[192+t];
      xxout[b*NP + n0 + t] = a;
    }
  }
}

// ---------------- MFMA bf16 GEMM y=W@x (+bias/base, fused in-GN, out-stats, out-max/min) ----------------
template<bool WRITE_Y, bool DO_STATS, bool DO_MAXMIN, bool IN_NORM>
__global__ __launch_bounds__(256) void mgemm_kernel(
    const float* __restrict__ W, int ldw,
    const float* __restrict__ x, long xldb,
    const float* __restrict__ bias, const float* __restrict__ basev,
    int O, int C, int gshift,
    float* __restrict__ y, float* __restrict__ stats,
    unsigned* __restrict__ mmax, unsigned* __restrict__ mmin,
    const float* __restrict__ instats, const float* __restrict__ igw,
    const float* __restrict__ igb, int igshift, float iinv)
{
  __shared__ __align__(16) char WlB[128*80];
  __shared__ __align__(16) char XtB[128*80];
  __shared__ float sred[16];
  __shared__ unsigned smax[128];
  __shared__ unsigned smin[128];

  const int b  = blockIdx.z;
  const int o0 = blockIdx.y*128;
  const int nb = blockIdx.x*128;
  const int t  = threadIdx.x;
  const int lane = t & 63;
  const int wid = t >> 6;
  const int wmo = wid >> 1, wno = wid & 1;
  const int lr = lane & 15, lg = lane >> 4;

  if (DO_STATS && t < 16) sred[t] = 0.f;
  if (DO_MAXMIN && t < 128){ smax[t] = 0u; smin[t] = 0xFFFFFFFFu; }

  f32x4 acc[4][4];
  #pragma unroll
  for(int i=0;i<4;i++)
    #pragma unroll
    for(int j=0;j<4;j++) acc[i][j] = (f32x4){0.f,0.f,0.f,0.f};

  const int so  = t & 127;
  const int scb = (t >> 7) << 5;
  const int xcg = t >> 5;
  const int xng = t & 31;

  for(int cc=0; cc<C; cc+=32){
    __syncthreads();
    {
      const float* wp = W + (long)(o0 + so)*ldw + cc + (scb>>1);
      #pragma unroll
      for(int j=0;j<4;j++){
        float4 f = *(const float4*)(wp + j*4);
        uint2 v = { bf2(f.x,f.y), bf2(f.z,f.w) };
        *(uint2*)ldsW(WlB, so, scb + j*8) = v;
      }
    }
    {
      const float* xp = x + (long)b*xldb + (long)(cc + xcg*4)*NP + nb + xng*4;
      float4 f0 = *(const float4*)(xp);
      float4 f1 = *(const float4*)(xp + NP);
      float4 f2 = *(const float4*)(xp + 2*NP);
      float4 f3 = *(const float4*)(xp + 3*NP);
      float X4[4][4] = {{f0.x,f0.y,f0.z,f0.w},{f1.x,f1.y,f1.z,f1.w},
                        {f2.x,f2.y,f2.z,f2.w},{f3.x,f3.y,f3.z,f3.w}};
      if (IN_NORM){
        #pragma unroll
        for(int i=0;i<4;i++){
          int c = cc + xcg*4 + i;
          int g = c >> igshift;
          const float* sp = instats + ((long)b*(C>>igshift) + g)*2;
          float mu = sp[0]*iinv;
          float var = sp[1]*iinv - mu*mu;
          float rs = rsqrtf(var + EPSV);
          float aa = rs*igw[c];
          float c2 = igb[c] - mu*aa;
          #pragma unroll
          for(int j=0;j<4;j++) X4[i][j] = fmaxf(X4[i][j]*aa + c2, 0.f);
        }
      }
      #pragma unroll
      for(int j=0;j<4;j++){
        uint2 v = { bf2(X4[0][j], X4[1][j]), bf2(X4[2][j], X4[3][j]) };
        *(uint2*)ldsX(XtB, xng*4 + j, xcg*8) = v;
      }
    }
    __syncthreads();
    bf16x8 afr[4], bfr[4];
    #pragma unroll
    for(int mi=0;mi<4;mi++) afr[mi] = *(const bf16x8*)ldsW(WlB, wmo*64 + mi*16 + lr, lg*16);
    #pragma unroll
    for(int nj=0;nj<4;nj++) bfr[nj] = *(const bf16x8*)ldsX(XtB, wno*64 + nj*16 + lr, lg*16);
    #pragma unroll
    for(int mi=0;mi<4;mi++)
      #pragma unroll
      for(int nj=0;nj<4;nj++)
        acc[mi][nj] = __builtin_amdgcn_mfma_f32_16x16x32_bf16(afr[mi], bfr[nj], acc[mi][nj], 0, 0, 0);
  }

  float bb4[4][4];
  #pragma unroll
  for(int mi=0;mi<4;mi++){
    #pragma unroll
    for(int r=0;r<4;r++){
      int o = o0 + wmo*64 + mi*16 + lg*4 + r;
      float v = 0.f;
      if (bias)  v += bias[o];
      if (basev) v += basev[(long)b*O + o];
      bb4[mi][r] = v;
    }
  }
  #pragma unroll
  for(int mi=0;mi<4;mi++)
    #pragma unroll
    for(int nj=0;nj<4;nj++)
      #pragma unroll
      for(int r=0;r<4;r++) acc[mi][nj][r] += bb4[mi][r];

  if (WRITE_Y){
    #pragma unroll
    for(int mi=0;mi<4;mi++)
      #pragma unroll
      for(int nj=0;nj<4;nj++)
        #pragma unroll
        for(int r=0;r<4;r++){
          int o = o0 + wmo*64 + mi*16 + lg*4 + r;
          y[((long)b*O + o)*NP + nb + wno*64 + nj*16 + lr] = acc[mi][nj][r];
        }
  }
  if (DO_STATS){
    #pragma unroll
    for(int mi=0;mi<4;mi++){
      float s = 0.f, s2 = 0.f;
      #pragma unroll
      for(int nj=0;nj<4;nj++)
        #pragma unroll
        for(int r=0;r<4;r++){ float v = acc[mi][nj][r]; s += v; s2 += v*v; }
      int gi = (wmo*64 + mi*16) >> gshift;
      atomicAdd(&sred[gi*2],   s);
      atomicAdd(&sred[gi*2+1], s2);
    }
  }
  if (DO_MAXMIN){
    #pragma unroll
    for(int mi=0;mi<4;mi++)
      #pragma unroll
      for(int r=0;r<4;r++){
        float mv = acc[mi][0][r], mw = acc[mi][0][r];
        #pragma unroll
        for(int nj=1;nj<4;nj++){ mv = fmaxf(mv, acc[mi][nj][r]); mw = fminf(mw, acc[mi][nj][r]); }
        int ol = wmo*64 + mi*16 + lg*4 + r;
        atomicMax(&smax[ol], fenc(mv));
        atomicMin(&smin[ol], fenc(mw));
      }
  }
  if (DO_STATS || DO_MAXMIN) __syncthreads();
  if (DO_STATS){
    int ngb = 128 >> gshift;
    if (t < ngb*2){
      atomicAdd(&stats[((long)b*(O>>gshift) + (o0>>gshift) + (t>>1))*2 + (t&1)], sred[t]);
    }
  }
  if (DO_MAXMIN){
    if (t < 128){
      atomicMax(&mmax[(long)b*O + o0 + t], smax[t]);
      atomicMin(&mmin[(long)b*O + o0 + t], smin[t]);
    }
  }
}

// ---------------- base1: recomputes xmax inline (fused) ----------------
// base1[b,o] = bs1[o] + sum_c Ws1[o][c] * relu(gn(max/min sel)); mu/rs hoisted to LDS.
__global__ __launch_bounds__(256) void base1_kernel(const float* __restrict__ Ws1, const float* __restrict__ bs1,
                                                    const unsigned* __restrict__ mmax, const unsigned* __restrict__ mmin,
                                                    const float* __restrict__ stats,
                                                    const float* __restrict__ gfw, const float* __restrict__ gfb,
                                                    float* __restrict__ base1){
  __shared__ float sred[4][8];
  __shared__ float smu[256], srs[256];
  const int o = blockIdx.x;
  const int t = threadIdx.x;
  const float inv_cnt = 1.f/(32.f*NP);
  {
    int bb = t >> 5, g = t & 31;
    const float* sp = stats + (bb*32 + g)*2;
    float mu = sp[0]*inv_cnt;
    float var = sp[1]*inv_cnt - mu*mu;
    smu[t] = mu;
    srs[t] = rsqrtf(var + EPSV);
  }
  __syncthreads();
  const float* wp = Ws1 + (long)o*1280;
  float acc[8];
  #pragma unroll
  for(int bb=0;bb<8;bb++) acc[bb]=0.f;
  #pragma unroll
  for(int cc=0;cc<4;cc++){
    int c = cc*256 + t;
    float w  = wp[c];
    float gw = gfw[c], gb = gfb[c];
    int g = c >> 5;
    #pragma unroll
    for(int bb=0;bb<8;bb++){
      int si = bb*32 + g;
      unsigned selu = (gw >= 0.f) ? mmax[bb*1024 + c] : mmin[bb*1024 + c];
      float v = fmaxf((fdec(selu) - smu[si])*srs[si]*gw + gb, 0.f);
      acc[bb] += w * v;
    }
  }
  #pragma unroll
  for(int bb=0;bb<8;bb++){
    float a = acc[bb];
    a += __shfl_xor(a,1);  a += __shfl_xor(a,2);  a += __shfl_xor(a,4);
    a += __shfl_xor(a,8);  a += __shfl_xor(a,16); a += __shfl_xor(a,32);
    acc[bb]=a;
  }
  if ((t&63)==0){
    #pragma unroll
    for(int bb=0;bb<8;bb++) sred[t>>6][bb]=acc[bb];
  }
  __syncthreads();
  if (t<8){
    float a = sred[0][t]+sred[1][t]+sred[2][t]+sred[3][t] + bs1[o];
    base1[t*512 + o] = a;
  }
}

// ---------------- final: fused GN3+relu + 50-class conv + log_softmax ----------------
__global__ __launch_bounds__(256) void s4_kernel(const float* __restrict__ h3raw,
                                                 const float* __restrict__ stats,
                                                 const float* __restrict__ gw, const float* __restrict__ gb,
                                                 const float* __restrict__ W,
                                                 const float* __restrict__ bias,
                                                 float* __restrict__ out){
  const int b = blockIdx.y;
  const int n = blockIdx.x*64 + (threadIdx.x>>2);
  const int cl = threadIdx.x & 3;
  const float inv_cnt = 1.f/(16.f*NP);
  float mu0, rs0, mu1, rs1;
  {
    const float* sp = stats + (b*8 + cl*2)*2;
    mu0 = sp[0]*inv_cnt;
    float var = sp[1]*inv_cnt - mu0*mu0;
    rs0 = rsqrtf(var + EPSV);
    const float* sp1 = stats + (b*8 + cl*2 + 1)*2;
    mu1 = sp1[0]*inv_cnt;
    float var1 = sp1[1]*inv_cnt - mu1*mu1;
    rs1 = rsqrtf(var1 + EPSV);
  }
  float hv[32];
  #pragma unroll
  for(int c=0;c<32;c++){
    int og = cl*32 + c;
    float rs = (c < 16) ? rs0 : rs1;
    float mu = (c < 16) ? mu0 : mu1;
    float a = rs*gw[og];
    float c2 = gb[og] - mu*a;
    float v = h3raw[((long)b*128 + og)*NP + n];
    hv[c] = fmaxf(v*a + c2, 0.f);
  }
  float zz[50];
  #pragma unroll
  for(int o=0;o<50;o++){
    const float* wp = W + o*128 + cl*32;
    float a = 0.f;
    #pragma unroll
    for(int c=0;c<32;c++) a += wp[c]*hv[c];
    a += __shfl_xor(a,1);
    a += __shfl_xor(a,2);
    zz[o] = a + bias[o];
  }
  float m = zz[0];
  #pragma unroll
  for(int o=1;o<50;o++) m = fmaxf(m, zz[o]);
  float s = 0.f;
  #pragma unroll
  for(int o=0;o<50;o++) s += __expf(zz[o]-m);
  float lse = m + __logf(s);
  #pragma unroll
  for(int o=0;o<50;o++){
    if ((o&3)==cl) out[((long)b*50+o)*NP+n] = zz[o]-lse;
  }
}

extern "C" void kernel_launch(void* const* d_in, const int* in_sizes, int n_in,
                              void* d_out, int out_size, void* d_ws, size_t ws_size,
                              hipStream_t stream)
{
  const float* x   = (const float*)d_in[0];
  const float* W1  = (const float*)d_in[1];
  const float* W2  = (const float*)d_in[2];
  const float* W3  = (const float*)d_in[3];
  const float* g1w = (const float*)d_in[4];
  const float* g1b = (const float*)d_in[5];
  const float* g2w = (const float*)d_in[6];
  const float* g2b = (const float*)d_in[7];
  const float* g3w = (const float*)d_in[8];
  const float* g3b = (const float*)d_in[9];
  const float* gfw = (const float*)d_in[10];
  const float* gfb = (const float*)d_in[11];
  const float* gs1w= (const float*)d_in[12];
  const float* gs1b= (const float*)d_in[13];
  const float* gs2w= (const float*)d_in[14];
  const float* gs2b= (const float*)d_in[15];
  const float* gs3w= (const float*)d_in[16];
  const float* gs3b= (const float*)d_in[17];
  const float* Wm  = (const float*)d_in[18];
  const float* bm  = (const float*)d_in[19];
  const float* Ws1 = (const float*)d_in[20];
  const float* bs1 = (const float*)d_in[21];
  const float* Ws2 = (const float*)d_in[22];
  const float* bs2 = (const float*)d_in[23];
  const float* Ws3 = (const float*)d_in[24];
  const float* bs3 = (const float*)d_in[25];
  const float* Ws4 = (const float*)d_in[26];
  const float* bs4 = (const float*)d_in[27];
  float* out = (float*)d_out;

  char* ws = (char*)d_ws;
  size_t off = 0;
  auto alloc = [&](size_t bytes)->char*{
    char* p = ws + off;
    off += (bytes + 255) & ~(size_t)255;
    return p;
  };
  char* zbase = alloc(6656 + 32768);
  float* estats1 = (float*)(zbase + 0);
  float* estats2 = (float*)(zbase + 512);
  float* estats3 = (float*)(zbase + 1024);
  float* mstats  = (float*)(zbase + 1536);
  float* s1stats = (float*)(zbase + 3584);
  float* s2stats = (float*)(zbase + 4608);
  float* s3stats = (float*)(zbase + 5632);
  unsigned* mmax = (unsigned*)(zbase + 6656);
  unsigned* mmin = (unsigned*)alloc(32768);
  float* base1 = (float*)alloc(8*512*4);
  float* feats = (float*)alloc((size_t)BN*256*NP*4);
  int*   idxb  = (int*)  alloc((size_t)BN*NP*KK*4);
  float* xxb   = (float*)alloc((size_t)BN*NP*4);
  unsigned* fhb = (unsigned*)alloc((size_t)BN*NP*64*2);
  unsigned* flb = (unsigned*)alloc((size_t)BN*NP*64*2);
  float* ya    = (float*)alloc((size_t)BN*NP*128*4);
  float* dd    = (float*)alloc((size_t)BN*NP*128*4);
  float* mx    = (float*)alloc((size_t)BN*NP*128*4);
  float* mn    = (float*)alloc((size_t)BN*NP*128*4);
  float* ybuf1 = (float*)alloc((size_t)BN*512*NP*4);
  float* ybuf2 = (float*)alloc((size_t)BN*256*NP*4);
  float* ybuf3 = (float*)alloc((size_t)BN*128*NP*4);

  // pk (41.9MB) aliases ya..mn — consumers strictly ordered after merge.
  unsigned* pk = (unsigned*)ya;
  const unsigned short* fh16 = (const unsigned short*)fhb;
  const unsigned short* fl16 = (const unsigned short*)flb;

  hipMemsetAsync(zbase, 0, 6656 + 32768, stream);
  hipMemsetAsync(mmin, 0xFF, 32768, stream);

  dim3 blk256(256);

  // ---- edge block 1 (C=3 -> 64) ----
  xx_kernel<<<dim3(NP/256, BN), blk256, 0, stream>>>(x, (long)3*NP, 3, xxb);
  knn1_kernel<<<dim3(NP/64, 8, BN), blk256, 0, stream>>>(x, xxb, pk);
  knnmerge_kernel<<<dim3(BN*NP/4), blk256, 0, stream>>>(pk, idxb);
  pcdual_kernel<3,64><<<dim3(NP/4, BN), blk256, 0, stream>>>(x, (long)3*NP, W1, ya, dd);
  egather_kernel<64><<<dim3(8*NP/32), blk256, 0, stream>>>(ya, dd, idxb, mx, mn, estats1);
  enorm_kernel<64,true,true><<<dim3(NP/64, 1, BN), blk256, 0, stream>>>(
      mx, mn, estats1, g1w, g1b, feats, 0, xxb, fhb, flb);

  // ---- edge block 2 (C=64 -> 64) ----
  knnf_kernel<<<dim3(NP/64, 8, BN), blk256, 0, stream>>>(fh16, fl16, xxb, pk);
  knnmerge_kernel<<<dim3(BN*NP/4), blk256, 0, stream>>>(pk, idxb);
  pcdualm_kernel<64,2><<<dim3(NP/64, 2, BN), blk256, 0, stream>>>(fh16, fl16, W2, ya, dd);
  egather_kernel<64><<<dim3(8*NP/32), blk256, 0, stream>>>(ya, dd, idxb, mx, mn, estats2);
  enorm_kernel<64,true,true><<<dim3(NP/64, 1, BN), blk256, 0, stream>>>(
      mx, mn, estats2, g2w, g2b, feats, 64, xxb, fhb, flb);

  // ---- edge block 3 (C=64 -> 128) ----
  knnf_kernel<<<dim3(NP/64, 8, BN), blk256, 0, stream>>>(fh16, fl16, xxb, pk);
  knnmerge_kernel<<<dim3(BN*NP/4), blk256, 0, stream>>>(pk, idxb);
  pcdualm_kernel<128,4><<<dim3(NP/64, 4, BN), blk256, 0, stream>>>(fh16, fl16, W3, ya, dd);
  egather_kernel<128><<<dim3(8*NP/32), blk256, 0, stream>>>(ya, dd, idxb, mx, mn, estats3);
  enorm_kernel<128,false,false><<<dim3(NP/64, 2, BN), blk256, 0, stream>>>(
      mx, mn, estats3, g3w, g3b, feats, 128, nullptr, nullptr, nullptr);

  // ---- global conv (Wm 1024x256): stats + per-(b,o) max/min only ----
  mgemm_kernel<false,true,true,false><<<dim3(16,8,BN), blk256, 0, stream>>>(
      Wm, 256, feats, (long)256*NP, bm, nullptr, 1024, 256, 5,
      nullptr, mstats, mmax, mmin, nullptr, nullptr, nullptr, 0, 0.f);
  base1_kernel<<<dim3(512), blk256, 0, stream>>>(Ws1, bs1, mmax, mmin, mstats, gfw, gfb, base1);

  // ---- seg conv 1 ----
  mgemm_kernel<true,true,false,false><<<dim3(16,4,BN), blk256, 0, stream>>>(
      Ws1 + 1024, 1280, feats, (long)256*NP, nullptr, base1, 512, 256, 5,
      ybuf1, s1stats, nullptr, nullptr, nullptr, nullptr, nullptr, 0, 0.f);

  // ---- seg conv 2 (fused GN1+relu on input) ----
  mgemm_kernel<true,true,false,true><<<dim3(16,2,BN), blk256, 0, stream>>>(
      Ws2, 512, ybuf1, (long)512*NP, bs2, nullptr, 256, 512, 4,
      ybuf2, s2stats, nullptr, nullptr, s1stats, gs1w, gs1b, 5, 1.f/(32.f*NP));

  // ---- seg conv 3 (fused GN2+relu on input) ----
  mgemm_kernel<true,true,false,true><<<dim3(16,1,BN), blk256, 0, stream>>>(
      Ws3, 256, ybuf2, (long)256*NP, bs3, nullptr, 128, 256, 4,
      ybuf3, s3stats, nullptr, nullptr, s2stats, gs2w, gs2b, 4, 1.f/(16.f*NP));

  // ---- final: fused GN3+relu + conv + log_softmax ----
  s4_kernel<<<dim3(NP/64, BN), blk256, 0, stream>>>(ybuf3, s3stats, gs3w, gs3b, Ws4, bs4, out);
}